// Round 3
// baseline (771.397 us; speedup 1.0000x reference)
//
#include <hip/hip_runtime.h>

// LinkPredictor: score[e] = w2 . relu(W1 . concat(h[src[e]], h[dst[e]]) + b1) + b2
// N_NODES=100000, N_EDGES=1600000, D=128, HIDDEN=256
//
// R15: coarse bucket-sort edge pass by src>>6.
//   R13/R14 post-mortem: edge pass is L2-fill-traffic bound at a constant
//   ~3.45 TB/s (time = FETCH/3.45); hit rate ~54% is footprint-invariant ->
//   capacity is a dead lever; must schedule the degree-16 reuse explicitly.
//   Sort edges into 1563 buckets of 64 src nodes (32 KB Us window/bucket):
//   Us fetch ~387 -> ~51 MB. Ud stays random (~387 MB). Edge blocks process
//   CONTIGUOUS sorted ranges + bijective chunked XCD swizzle (m204) so a
//   bucket stays in one XCD's L2. hist zero fused into cvt; hist atomics
//   fused into u_gemm3 (hidden under DMA); +2 dispatches (scan, scatter).
//   u_gemm3 also XCD-chunked so the 4 blocks per A-tile share L2 (-75 MB).
//   Predict: edge FETCH 751->~470 MB, edge dur 225->~140 us, total ~310 us.

#define NNODES 100000
#define E_TOTAL 1600000
#define D 128
#define K2 256
#define H 256
#define NBUCK ((NNODES + 63) >> 6)   // 1563 buckets of 64 src nodes
#define EDGE_GRID 3125               // 3125 blk * 16 grp * 8 chunks * 4 edges = 1.6M

typedef short bf16x8 __attribute__((ext_vector_type(8)));
typedef float f32x4 __attribute__((ext_vector_type(4)));
typedef const __attribute__((address_space(1))) unsigned short* gas_t;
typedef __attribute__((address_space(3))) unsigned short* las_t;

__device__ __forceinline__ unsigned short f2bf(float f) {
    unsigned u = __float_as_uint(f);
    u += 0x7fff + ((u >> 16) & 1);   // round-to-nearest-even
    return (unsigned short)(u >> 16);
}
__device__ __forceinline__ float bf2f(unsigned short s) {
    return __uint_as_float((unsigned)s << 16);
}

// m204 bijective chunked XCD swizzle: consecutive output ids -> same XCD.
__device__ __forceinline__ int xcd_chunk(int orig, int nwg) {
    const int q = nwg >> 3, r = nwg & 7;
    const int x = orig & 7, s = orig >> 3;
    return (x < r ? x * (q + 1) : r * (q + 1) + (x - r) * q) + s;
}

// ---------------- cvt: h and W1 -> bf16 (+ hist zero fused) ----------------
__global__ void cvt_kernel(const float* __restrict__ h, const float* __restrict__ w1,
                           unsigned short* __restrict__ hbf, unsigned short* __restrict__ w1bf,
                           int n4h, int n4w, int* __restrict__ hist, int nz) {
    int i = blockIdx.x * blockDim.x + threadIdx.x;
    if (i >= n4h + n4w) {
        int z = i - (n4h + n4w);
        if (z < nz) hist[z] = 0;
        return;
    }
    const float* s; unsigned short* d; int j;
    if (i < n4h) { s = h; d = hbf; j = i; }
    else { s = w1; d = w1bf; j = i - n4h; }
    float4 v = ((const float4*)s)[j];
    ushort4 o;
    o.x = f2bf(v.x); o.y = f2bf(v.y); o.z = f2bf(v.z); o.w = f2bf(v.w);
    ((ushort4*)d)[j] = o;
}

// ---------------- u_gemm v3: N-split, direct C-layout stores ----------------
// R15: block decode goes through xcd_chunk so the 4 blocks of one A-tile
// (consecutive L) land on the same XCD -> A fetched once + 3 L2 hits.
// Fused src histogram: 6252*256 threads >= 1.6M edges; atomics hidden
// under the A-tile DMA. hist may be null (mid-ws path).
__global__ __launch_bounds__(256, 4) void u_gemm3(
    const unsigned short* __restrict__ hbf,
    const unsigned short* __restrict__ w1bf,
    const float* __restrict__ b1,
    unsigned short* __restrict__ Us,
    unsigned short* __restrict__ Ud,
    const int* __restrict__ srcE,
    int* __restrict__ hist)
{
    __shared__ __align__(16) unsigned short A[64 * 128];   // 16384 B

    const int tid = threadIdx.x;
    const int wave = tid >> 6;
    const int lane = tid & 63;
    const int l15 = lane & 15;
    const int quad = lane >> 4;

    const int L = xcd_chunk(blockIdx.x, gridDim.x);
    const int tile = L >> 2;
    const int half = (L >> 1) & 1;
    const int nh = L & 1;
    const int r0 = tile * 64;
    int rows = NNODES - r0; if (rows > 64) rows = 64;
    const int koff = half * 128;
    unsigned short* U = half ? Ud : Us;

    // --- issue async stage of A (16 KB), XOR swizzle c = p ^ (r&15) ---
#pragma unroll
    for (int it = 0; it < 4; ++it) {
        const int s = it * 256 + tid;      // 16B slot 0..1023
        const int r = s >> 4;              // row 0..63
        const int p = s & 15;              // position chunk
        const int c = p ^ (r & 15);        // content chunk
        if (r < rows)
            __builtin_amdgcn_global_load_lds(
                (gas_t)(hbf + (size_t)(r0 + r) * D + c * 8),
                (las_t)(A + it * 2048 + wave * 512), 16, 0, 0);
    }

    // --- fused src histogram (hidden under DMA) ---
    if (hist) {
        const int gid = blockIdx.x * 256 + tid;
        if (gid < E_TOTAL) atomicAdd(&hist[srcE[gid] >> 6], 1);
    }

    // --- B fragments + bias while DMA is in flight ---
    bf16x8 B[4][2];
    float bias[2];
#pragma unroll
    for (int nt = 0; nt < 2; ++nt) {
        const int n = nh * 128 + wave * 32 + nt * 16 + l15;
        bias[nt] = half ? 0.f : b1[n];
#pragma unroll
        for (int kit = 0; kit < 4; ++kit)
            B[kit][nt] = *(const bf16x8*)(w1bf + (size_t)n * K2 + koff + kit * 32 + quad * 8);
    }

    __syncthreads();   // vmcnt(0): A landed

    f32x4 acc[4][2];
    const f32x4 zero = {0.f, 0.f, 0.f, 0.f};
#pragma unroll
    for (int ms = 0; ms < 4; ++ms)
#pragma unroll
        for (int nt = 0; nt < 2; ++nt)
            acc[ms][nt] = zero;

#pragma unroll
    for (int kit = 0; kit < 4; ++kit) {
        bf16x8 a[4];
#pragma unroll
        for (int ms = 0; ms < 4; ++ms) {
            const int row = ms * 16 + l15;
            const int p = (kit * 4 + quad) ^ l15;
            a[ms] = *(const bf16x8*)&A[row * 128 + p * 8];
        }
#pragma unroll
        for (int ms = 0; ms < 4; ++ms)
#pragma unroll
            for (int nt = 0; nt < 2; ++nt)
                acc[ms][nt] = __builtin_amdgcn_mfma_f32_16x16x32_bf16(
                    a[ms], B[kit][nt], acc[ms][nt], 0, 0, 0);
    }

    // --- direct permuted store: dword per (ms,r), 64B segment per quad ---
    const int coff = nh * 128 + wave * 32 + l15 * 2;   // short offset in U row
#pragma unroll
    for (int ms = 0; ms < 4; ++ms) {
#pragma unroll
        for (int r = 0; r < 4; ++r) {
            const int m = ms * 16 + quad * 4 + r;
            if (m < rows) {
                const unsigned lo = f2bf(acc[ms][0][r] + bias[0]);
                const unsigned hi = f2bf(acc[ms][1][r] + bias[1]);
                *(unsigned*)(U + (size_t)(r0 + m) * H + coff) = lo | (hi << 16);
            }
        }
    }
}

// ---------------- scan: exclusive prefix over NBUCK bucket counts ----------
// Single block, 256 threads x 7 elems (1792 >= 1563). Writes atomic cursors.
__global__ void scan_kernel(const int* __restrict__ hist, int* __restrict__ cursor) {
    __shared__ int tsum[256];
    const int t = threadIdx.x;
    int loc[7];
    int s = 0;
#pragma unroll
    for (int j = 0; j < 7; ++j) {
        const int idx = t * 7 + j;
        const int v = (idx < NBUCK) ? hist[idx] : 0;
        loc[j] = s; s += v;
    }
    tsum[t] = s;
    __syncthreads();
    for (int off = 1; off < 256; off <<= 1) {
        const int v = (t >= off) ? tsum[t - off] : 0;
        __syncthreads();
        tsum[t] += v;
        __syncthreads();
    }
    const int excl = tsum[t] - s;   // exclusive prefix of this thread's chunk
#pragma unroll
    for (int j = 0; j < 7; ++j) {
        const int idx = t * 7 + j;
        if (idx < NBUCK) cursor[idx] = excl + loc[j];
    }
}

// ---------------- scatter: bucket-sort edges by src>>6 ---------------------
__global__ __launch_bounds__(256) void scatter_kernel(
    const int* __restrict__ srcE, const int* __restrict__ dstE,
    int* __restrict__ cursor,
    int* __restrict__ ss, int* __restrict__ sd, int* __restrict__ si)
{
    const int e = blockIdx.x * 256 + threadIdx.x;   // grid covers 1.6M exactly
    const int s = srcE[e];
    const int d = dstE[e];
    const int p = atomicAdd(&cursor[s >> 6], 1);
    ss[p] = s; sd[p] = d; si[p] = e;
}

// ---------------- edge pass (R15: sorted, contiguous, XCD-chunked) ---------
// U' layout: within each 32-col block, c'' = l15*2+nt holds n'' = nt*16+l15.
// 16-lane group handles 8 consecutive 4-edge chunks (32 sorted edges).
// Blocks xcd_chunk-swizzled: contiguous sorted ranges stay on one XCD ->
// each bucket's 32 KB Us window is fetched once into that XCD's L2.
__global__ __launch_bounds__(256) void edge_score_sorted(
    const unsigned short* __restrict__ Us,
    const unsigned short* __restrict__ Ud,
    const int* __restrict__ ss,
    const int* __restrict__ sd,
    const int* __restrict__ si,
    const float* __restrict__ w2,
    const float* __restrict__ b2p,
    float* __restrict__ out)
{
    const int b = xcd_chunk(blockIdx.x, gridDim.x);
    const int tid = threadIdx.x;
    const int l = tid & 15;
    const int grp = b * 16 + (tid >> 4);   // 0..49999

    float w2v[16];
#pragma unroll
    for (int j = 0; j < 16; ++j) {
        const int cp = l * 16 + j;
        const int n = (cp & ~31) + ((cp & 1) << 4) + ((cp & 31) >> 1);
        w2v[j] = w2[n];
    }
    const float b2 = *b2p;

    const int g0 = grp * 8;
    for (int g = g0; g < g0 + 8; ++g) {
        const int e0 = g * 4;
        const int4 s4 = *(const int4*)(ss + e0);
        const int4 d4 = *(const int4*)(sd + e0);
        const int4 i4 = *(const int4*)(si + e0);
        const int sv[4] = {s4.x, s4.y, s4.z, s4.w};
        const int dv[4] = {d4.x, d4.y, d4.z, d4.w};

        bf16x8 u[4][2], v[4][2];
#pragma unroll
        for (int k = 0; k < 4; ++k) {
            const bf16x8* us = (const bf16x8*)(Us + (size_t)sv[k] * H + l * 16);
            const bf16x8* ud = (const bf16x8*)(Ud + (size_t)dv[k] * H + l * 16);
            u[k][0] = us[0]; u[k][1] = us[1];
            v[k][0] = ud[0]; v[k][1] = ud[1];
        }

        float4 res;
        float* resp = (float*)&res;
#pragma unroll
        for (int k = 0; k < 4; ++k) {
            float acc = 0.f;
#pragma unroll
            for (int j = 0; j < 8; ++j) {
                float hv = bf2f((unsigned short)u[k][0][j]) + bf2f((unsigned short)v[k][0][j]);
                acc = fmaf(fmaxf(hv, 0.f), w2v[j], acc);
            }
#pragma unroll
            for (int j = 0; j < 8; ++j) {
                float hv = bf2f((unsigned short)u[k][1][j]) + bf2f((unsigned short)v[k][1][j]);
                acc = fmaf(fmaxf(hv, 0.f), w2v[j + 8], acc);
            }
            acc += __shfl_xor(acc, 1, 16);
            acc += __shfl_xor(acc, 2, 16);
            acc += __shfl_xor(acc, 4, 16);
            acc += __shfl_xor(acc, 8, 16);
            resp[k] = acc + b2;
        }
        if (l == 0) {
            out[i4.x] = res.x;
            out[i4.y] = res.y;
            out[i4.z] = res.z;
            out[i4.w] = res.w;
        }
    }
}

// ---------------- edge pass (R12 unsorted, mid-ws fallback) ----------------
__global__ __launch_bounds__(256) void edge_score(
    const unsigned short* __restrict__ Us,
    const unsigned short* __restrict__ Ud,
    const int* __restrict__ srcE,
    const int* __restrict__ dstE,
    const float* __restrict__ w2,
    const float* __restrict__ b2p,
    float* __restrict__ out)
{
    const int gt = blockIdx.x * 256 + threadIdx.x;
    const int l = gt & 15;
    const int q = gt >> 4;
    const int Q = (gridDim.x * 256) >> 4;
    const int NGRP = E_TOTAL / 4;   // 400000

    float w2v[16];
#pragma unroll
    for (int j = 0; j < 16; ++j) {
        const int cp = l * 16 + j;
        const int n = (cp & ~31) + ((cp & 1) << 4) + ((cp & 31) >> 1);
        w2v[j] = w2[n];
    }
    const float b2 = *b2p;

    for (int g = q; g < NGRP; g += Q) {
        const int e0 = g * 4;
        const int4 s4 = *(const int4*)(srcE + e0);
        const int4 d4 = *(const int4*)(dstE + e0);
        const int sv[4] = {s4.x, s4.y, s4.z, s4.w};
        const int dv[4] = {d4.x, d4.y, d4.z, d4.w};

        bf16x8 u[4][2], v[4][2];
#pragma unroll
        for (int k = 0; k < 4; ++k) {
            const bf16x8* us = (const bf16x8*)(Us + (size_t)sv[k] * H + l * 16);
            const bf16x8* ud = (const bf16x8*)(Ud + (size_t)dv[k] * H + l * 16);
            u[k][0] = us[0]; u[k][1] = us[1];
            v[k][0] = ud[0]; v[k][1] = ud[1];
        }

        float4 res;
        float* resp = (float*)&res;
#pragma unroll
        for (int k = 0; k < 4; ++k) {
            float acc = 0.f;
#pragma unroll
            for (int j = 0; j < 8; ++j) {
                float hv = bf2f((unsigned short)u[k][0][j]) + bf2f((unsigned short)v[k][0][j]);
                acc = fmaf(fmaxf(hv, 0.f), w2v[j], acc);
            }
#pragma unroll
            for (int j = 0; j < 8; ++j) {
                float hv = bf2f((unsigned short)u[k][1][j]) + bf2f((unsigned short)v[k][1][j]);
                acc = fmaf(fmaxf(hv, 0.f), w2v[j + 8], acc);
            }
            acc += __shfl_xor(acc, 1, 16);
            acc += __shfl_xor(acc, 2, 16);
            acc += __shfl_xor(acc, 4, 16);
            acc += __shfl_xor(acc, 8, 16);
            resp[k] = acc + b2;
        }
        if (l == 0) *(float4*)(out + e0) = res;
    }
}

// ======================= R4 fallback (ws too small) ======================

#define TILE_M 32
#define NTILES (E_TOTAL / TILE_M)
#define GRID 2500

#if defined(__has_attribute)
#if __has_attribute(amdgpu_waves_per_eu)
#define LB __launch_bounds__(256) __attribute__((amdgpu_waves_per_eu(2, 2)))
#else
#define LB __launch_bounds__(256, 2)
#endif
#else
#define LB __launch_bounds__(256, 2)
#endif

__global__ LB void edge_mlp(
    const unsigned short* __restrict__ hbf,
    const int* __restrict__ srcE,
    const int* __restrict__ dstE,
    const unsigned short* __restrict__ w1bf,
    const float* __restrict__ b1,
    const float* __restrict__ w2,
    const float* __restrict__ b2p,
    float* __restrict__ out)
{
    __shared__ __align__(16) unsigned short X[2][TILE_M * K2];
    __shared__ float red[2][TILE_M][5];

    const int tid = threadIdx.x;
    const int wave = tid >> 6;
    const int lane = tid & 63;
    const int lane15 = lane & 15;
    const int quad = lane >> 4;

    bf16x8 B[8][4];
#pragma unroll
    for (int kit = 0; kit < 8; ++kit)
#pragma unroll
        for (int nt = 0; nt < 4; ++nt) {
            int n = wave * 64 + nt * 16 + lane15;
            int k = kit * 32 + quad * 8;
            B[kit][nt] = *(const bf16x8*)(w1bf + n * K2 + k);
        }

    float b1v[4], w2v[4];
#pragma unroll
    for (int nt = 0; nt < 4; ++nt) {
        int n = wave * 64 + nt * 16 + lane15;
        b1v[nt] = b1[n];
        w2v[nt] = w2[n];
    }
    const float b2 = *b2p;

    const int r_off = tid >> 5;
    const int c = (tid & 31) ^ (r_off & 7);
    const int half = c >> 4;
    const int fc = c & 15;
    const int* idx_base = half ? dstE : srcE;
    const int gshort = fc * 8;

    const int t0 = blockIdx.x;
    int inode[4];

#pragma unroll
    for (int it = 0; it < 4; ++it)
        inode[it] = idx_base[t0 * TILE_M + it * 8 + r_off];
#pragma unroll
    for (int it = 0; it < 4; ++it)
        __builtin_amdgcn_global_load_lds(
            (gas_t)(hbf + inode[it] * D + gshort),
            (las_t)(&X[0][0] + it * 2048 + wave * 512), 16, 0, 0);
    {
        const int t1 = t0 + GRID;
#pragma unroll
        for (int it = 0; it < 4; ++it)
            inode[it] = idx_base[t1 * TILE_M + it * 8 + r_off];
    }

    int buf = 0;
    int prev_eb = -1;

    for (int tile = t0; tile < NTILES; tile += GRID) {
        __syncthreads();

        const int nt1 = tile + GRID;
        if (nt1 < NTILES) {
            unsigned short* Xn = &X[buf ^ 1][0];
#pragma unroll
            for (int it = 0; it < 4; ++it)
                __builtin_amdgcn_global_load_lds(
                    (gas_t)(hbf + inode[it] * D + gshort),
                    (las_t)(Xn + it * 2048 + wave * 512), 16, 0, 0);
        }
        const int nt2 = tile + 2 * GRID;
        if (nt2 < NTILES) {
            const int eb2 = nt2 * TILE_M;
#pragma unroll
            for (int it = 0; it < 4; ++it)
                inode[it] = idx_base[eb2 + it * 8 + r_off];
        }
        if (prev_eb >= 0 && tid < TILE_M) {
            float s = b2;
#pragma unroll
            for (int w = 0; w < 4; ++w) s += red[buf ^ 1][tid][w];
            out[prev_eb + tid] = s;
        }

        const unsigned short* Xc = &X[buf][0];
        f32x4 acc[2][4];
        const f32x4 zero = {0.f, 0.f, 0.f, 0.f};
#pragma unroll
        for (int ms = 0; ms < 2; ++ms)
#pragma unroll
            for (int nt = 0; nt < 4; ++nt)
                acc[ms][nt] = zero;

#pragma unroll
        for (int kit = 0; kit < 8; ++kit) {
            const int p8 = (((kit * 4 + quad) ^ (lane15 & 7))) * 8;
            bf16x8 a[2];
#pragma unroll
            for (int ms = 0; ms < 2; ++ms)
                a[ms] = *(const bf16x8*)&Xc[(ms * 16 + lane15) * K2 + p8];
#pragma unroll
            for (int ms = 0; ms < 2; ++ms)
#pragma unroll
                for (int nt = 0; nt < 4; ++nt)
                    acc[ms][nt] = __builtin_amdgcn_mfma_f32_16x16x32_bf16(
                        a[ms], B[kit][nt], acc[ms][nt], 0, 0, 0);
        }

#pragma unroll
        for (int ms = 0; ms < 2; ++ms)
#pragma unroll
            for (int r = 0; r < 4; ++r) {
                float p = 0.f;
#pragma unroll
                for (int nt = 0; nt < 4; ++nt) {
                    float hv = acc[ms][nt][r] + b1v[nt];
                    p = fmaf(fmaxf(hv, 0.f), w2v[nt], p);
                }
                p += __shfl_xor(p, 1, 16);
                p += __shfl_xor(p, 2, 16);
                p += __shfl_xor(p, 4, 16);
                p += __shfl_xor(p, 8, 16);
                if (lane15 == 0) red[buf][ms * 16 + quad * 4 + r][wave] = p;
            }
        prev_eb = tile * TILE_M;
        buf ^= 1;
    }

    __syncthreads();
    if (prev_eb >= 0 && tid < TILE_M) {
        float s = b2;
#pragma unroll
        for (int w = 0; w < 4; ++w) s += red[buf ^ 1][tid][w];
        out[prev_eb + tid] = s;
    }
}

// ================================ launch ================================

extern "C" void kernel_launch(void* const* d_in, const int* in_sizes, int n_in,
                              void* d_out, int out_size, void* d_ws, size_t ws_size,
                              hipStream_t stream) {
    const float* h    = (const float*)d_in[0];
    const int*   srcE = (const int*)d_in[1];
    const int*   dstE = (const int*)d_in[2];
    const float* W1   = (const float*)d_in[3];
    const float* b1   = (const float*)d_in[4];
    const float* w2   = (const float*)d_in[5];
    const float* b2   = (const float*)d_in[6];
    float* out = (float*)d_out;

    char* ws = (char*)d_ws;
    const size_t offUs   = 0;                        // 51,200,000 B
    const size_t offUd   = 51200000;                 // 51,200,000 B
    const size_t offHbf  = 102400000;                // 25,600,000 B
    const size_t offW1bf = 128000000;                // 131,072 B
    const size_t need    = offW1bf + 131072;         // 128,131,072 B
    // R15 sort extras
    const size_t offHist = need;                     // 8,192 B (1563 ints)
    const size_t offCur  = offHist + 8192;           // 8,192 B
    const size_t offSS   = offCur + 8192;            // 6,400,000 B
    const size_t offSD   = offSS + 6400000;          // 6,400,000 B
    const size_t offSI   = offSD + 6400000;          // 6,400,000 B
    const size_t need2   = offSI + 6400000;          // 147,347,456 B

    if (ws_size >= need) {
        unsigned short* Us   = (unsigned short*)(ws + offUs);
        unsigned short* Ud   = (unsigned short*)(ws + offUd);
        unsigned short* hbf  = (unsigned short*)(ws + offHbf);
        unsigned short* w1bf = (unsigned short*)(ws + offW1bf);
        const bool sorted = (ws_size >= need2);
        int* hist = sorted ? (int*)(ws + offHist) : (int*)nullptr;
        int* cur  = (int*)(ws + offCur);
        int* ss   = (int*)(ws + offSS);
        int* sd   = (int*)(ws + offSD);
        int* si   = (int*)(ws + offSI);

        int n4h = NNODES * D / 4, n4w = H * K2 / 4;
        const int nz = sorted ? NBUCK : 0;
        cvt_kernel<<<(n4h + n4w + nz + 255) / 256, 256, 0, stream>>>(
            h, W1, hbf, w1bf, n4h, n4w, hist, nz);
        u_gemm3<<<4 * ((NNODES + 63) / 64), 256, 0, stream>>>(
            hbf, w1bf, b1, Us, Ud, srcE, hist);
        if (sorted) {
            scan_kernel<<<1, 256, 0, stream>>>(hist, cur);
            scatter_kernel<<<E_TOTAL / 256, 256, 0, stream>>>(srcE, dstE, cur, ss, sd, si);
            edge_score_sorted<<<EDGE_GRID, 256, 0, stream>>>(Us, Ud, ss, sd, si, w2, b2, out);
        } else {
            edge_score<<<4096, 256, 0, stream>>>(Us, Ud, srcE, dstE, w2, b2, out);
        }
    } else {
        unsigned short* hbf  = (unsigned short*)d_ws;
        unsigned short* w1bf = hbf + (size_t)NNODES * D;
        int n4h = NNODES * D / 4, n4w = H * K2 / 4;
        cvt_kernel<<<(n4h + n4w + 255) / 256, 256, 0, stream>>>(
            h, W1, hbf, w1bf, n4h, n4w, nullptr, 0);
        edge_mlp<<<GRID, 256, 0, stream>>>(hbf, srcE, dstE, w1bf, b1, w2, b2, out);
    }
}

// Round 4
// 430.427 us; speedup vs baseline: 1.7922x; 1.7922x over previous
//
#include <hip/hip_runtime.h>

// LinkPredictor: score[e] = w2 . relu(W1 . concat(h[src[e]], h[dst[e]]) + b1) + b2
// N_NODES=100000, N_EDGES=1600000, D=128, HIDDEN=256
//
// R16: sort kept, atomic contention removed.
//   R15 post-mortem: u_gemm3 60->243 us was the fused histogram's 1.6M
//   device-scope atomics onto 49 cache lines (plus swizzle); scatter_kernel
//   had the same pattern (~200 us, hidden below top-5). edge_score_sorted
//   itself was never measured. Fix:
//   (1) u_gemm3 reverted to R12 form (no hist, no swizzle) -> ~60 us.
//   (2) hist_kernel: 256 blocks, LDS-privatized histogram, one global
//       atomicAdd per nonzero bucket per block (~400K atomics, 256-way).
//   (3) scatter3: LDS count -> per-bucket range reserve (1 global atomic
//       per bucket per block) -> LDS-cursor scatter. No hot global cursors.
//   Predict: gemm 243->60, hist~10, scan~5, scatter~20-25,
//   edge_sorted FETCH ~460 MB dur ~140 us, total ~320 us.

#define NNODES 100000
#define E_TOTAL 1600000
#define D 128
#define K2 256
#define H 256
#define NBUCK ((NNODES + 63) >> 6)   // 1563 buckets of 64 src nodes
#define EDGE_GRID 3125               // 3125 blk * 16 grp * 8 chunks * 4 edges = 1.6M
#define SORT_GRID 256                // hist/scatter blocks
#define EPB (E_TOTAL / SORT_GRID)    // 6250 edges per sort block

typedef short bf16x8 __attribute__((ext_vector_type(8)));
typedef float f32x4 __attribute__((ext_vector_type(4)));
typedef const __attribute__((address_space(1))) unsigned short* gas_t;
typedef __attribute__((address_space(3))) unsigned short* las_t;

__device__ __forceinline__ unsigned short f2bf(float f) {
    unsigned u = __float_as_uint(f);
    u += 0x7fff + ((u >> 16) & 1);   // round-to-nearest-even
    return (unsigned short)(u >> 16);
}
__device__ __forceinline__ float bf2f(unsigned short s) {
    return __uint_as_float((unsigned)s << 16);
}

// m204 bijective chunked XCD swizzle: consecutive output ids -> same XCD.
__device__ __forceinline__ int xcd_chunk(int orig, int nwg) {
    const int q = nwg >> 3, r = nwg & 7;
    const int x = orig & 7, s = orig >> 3;
    return (x < r ? x * (q + 1) : r * (q + 1) + (x - r) * q) + s;
}

// ---------------- cvt: h and W1 -> bf16 (+ hist zero fused) ----------------
__global__ void cvt_kernel(const float* __restrict__ h, const float* __restrict__ w1,
                           unsigned short* __restrict__ hbf, unsigned short* __restrict__ w1bf,
                           int n4h, int n4w, int* __restrict__ hist, int nz) {
    int i = blockIdx.x * blockDim.x + threadIdx.x;
    if (i >= n4h + n4w) {
        int z = i - (n4h + n4w);
        if (z < nz) hist[z] = 0;
        return;
    }
    const float* s; unsigned short* d; int j;
    if (i < n4h) { s = h; d = hbf; j = i; }
    else { s = w1; d = w1bf; j = i - n4h; }
    float4 v = ((const float4*)s)[j];
    ushort4 o;
    o.x = f2bf(v.x); o.y = f2bf(v.y); o.z = f2bf(v.z); o.w = f2bf(v.w);
    ((ushort4*)d)[j] = o;
}

// ---------------- u_gemm v3 (R12 form: no swizzle, no hist) ----------------
// blockIdx bx: tile = bx>>2 (64 node rows), half = (bx>>1)&1 (0: Us + b1 fold,
// 1: Ud), nh = bx&1 (cols 0-127 vs 128-255 of the half's output).
__global__ __launch_bounds__(256, 4) void u_gemm3(
    const unsigned short* __restrict__ hbf,
    const unsigned short* __restrict__ w1bf,
    const float* __restrict__ b1,
    unsigned short* __restrict__ Us,
    unsigned short* __restrict__ Ud)
{
    __shared__ __align__(16) unsigned short A[64 * 128];   // 16384 B

    const int tid = threadIdx.x;
    const int wave = tid >> 6;
    const int lane = tid & 63;
    const int l15 = lane & 15;
    const int quad = lane >> 4;

    const int tile = blockIdx.x >> 2;
    const int half = (blockIdx.x >> 1) & 1;
    const int nh = blockIdx.x & 1;
    const int r0 = tile * 64;
    int rows = NNODES - r0; if (rows > 64) rows = 64;
    const int koff = half * 128;
    unsigned short* U = half ? Ud : Us;

    // --- issue async stage of A (16 KB), XOR swizzle c = p ^ (r&15) ---
#pragma unroll
    for (int it = 0; it < 4; ++it) {
        const int s = it * 256 + tid;      // 16B slot 0..1023
        const int r = s >> 4;              // row 0..63
        const int p = s & 15;              // position chunk
        const int c = p ^ (r & 15);        // content chunk
        if (r < rows)
            __builtin_amdgcn_global_load_lds(
                (gas_t)(hbf + (size_t)(r0 + r) * D + c * 8),
                (las_t)(A + it * 2048 + wave * 512), 16, 0, 0);
    }

    // --- B fragments + bias while DMA is in flight ---
    bf16x8 B[4][2];
    float bias[2];
#pragma unroll
    for (int nt = 0; nt < 2; ++nt) {
        const int n = nh * 128 + wave * 32 + nt * 16 + l15;
        bias[nt] = half ? 0.f : b1[n];
#pragma unroll
        for (int kit = 0; kit < 4; ++kit)
            B[kit][nt] = *(const bf16x8*)(w1bf + (size_t)n * K2 + koff + kit * 32 + quad * 8);
    }

    __syncthreads();   // vmcnt(0): A landed

    f32x4 acc[4][2];
    const f32x4 zero = {0.f, 0.f, 0.f, 0.f};
#pragma unroll
    for (int ms = 0; ms < 4; ++ms)
#pragma unroll
        for (int nt = 0; nt < 2; ++nt)
            acc[ms][nt] = zero;

#pragma unroll
    for (int kit = 0; kit < 4; ++kit) {
        bf16x8 a[4];
#pragma unroll
        for (int ms = 0; ms < 4; ++ms) {
            const int row = ms * 16 + l15;
            const int p = (kit * 4 + quad) ^ l15;
            a[ms] = *(const bf16x8*)&A[row * 128 + p * 8];
        }
#pragma unroll
        for (int ms = 0; ms < 4; ++ms)
#pragma unroll
            for (int nt = 0; nt < 2; ++nt)
                acc[ms][nt] = __builtin_amdgcn_mfma_f32_16x16x32_bf16(
                    a[ms], B[kit][nt], acc[ms][nt], 0, 0, 0);
    }

    // --- direct permuted store: dword per (ms,r), 64B segment per quad ---
    const int coff = nh * 128 + wave * 32 + l15 * 2;   // short offset in U row
#pragma unroll
    for (int ms = 0; ms < 4; ++ms) {
#pragma unroll
        for (int r = 0; r < 4; ++r) {
            const int m = ms * 16 + quad * 4 + r;
            if (m < rows) {
                const unsigned lo = f2bf(acc[ms][0][r] + bias[0]);
                const unsigned hi = f2bf(acc[ms][1][r] + bias[1]);
                *(unsigned*)(U + (size_t)(r0 + m) * H + coff) = lo | (hi << 16);
            }
        }
    }
}

// ---------------- hist: LDS-privatized src-bucket histogram ----------------
// 256 blocks x 6250 edges. LDS atomics for counting; one global atomicAdd
// per nonzero bucket per block (~400K total, 256-way contention max).
__global__ __launch_bounds__(256) void hist_kernel(
    const int* __restrict__ srcE, int* __restrict__ hist)
{
    __shared__ int lh[NBUCK];
    const int tid = threadIdx.x;
    const int base = blockIdx.x * EPB;
    for (int i = tid; i < NBUCK; i += 256) lh[i] = 0;
    __syncthreads();
    for (int i = tid; i < EPB; i += 256)
        atomicAdd(&lh[srcE[base + i] >> 6], 1);
    __syncthreads();
    for (int i = tid; i < NBUCK; i += 256) {
        const int c = lh[i];
        if (c) atomicAdd(&hist[i], c);
    }
}

// ---------------- scan: exclusive prefix over NBUCK bucket counts ----------
// Single block, 256 threads x 7 elems (1792 >= 1563). Writes atomic cursors.
__global__ void scan_kernel(const int* __restrict__ hist, int* __restrict__ cursor) {
    __shared__ int tsum[256];
    const int t = threadIdx.x;
    int loc[7];
    int s = 0;
#pragma unroll
    for (int j = 0; j < 7; ++j) {
        const int idx = t * 7 + j;
        const int v = (idx < NBUCK) ? hist[idx] : 0;
        loc[j] = s; s += v;
    }
    tsum[t] = s;
    __syncthreads();
    for (int off = 1; off < 256; off <<= 1) {
        const int v = (t >= off) ? tsum[t - off] : 0;
        __syncthreads();
        tsum[t] += v;
        __syncthreads();
    }
    const int excl = tsum[t] - s;   // exclusive prefix of this thread's chunk
#pragma unroll
    for (int j = 0; j < 7; ++j) {
        const int idx = t * 7 + j;
        if (idx < NBUCK) cursor[idx] = excl + loc[j];
    }
}

// ---------------- scatter v3: range-reserve, LDS-cursor scatter ------------
// Same 256-block ranges as hist. Pass 1: LDS count. Pass 2: reserve a
// contiguous range per (block,bucket) with ONE global atomicAdd. Pass 3:
// LDS-cursor scatter into the reserved ranges.
__global__ __launch_bounds__(256) void scatter3(
    const int* __restrict__ srcE, const int* __restrict__ dstE,
    int* __restrict__ cursor,
    int* __restrict__ ss, int* __restrict__ sd, int* __restrict__ si)
{
    __shared__ int lh[NBUCK];
    __shared__ int lbase[NBUCK];
    const int tid = threadIdx.x;
    const int base = blockIdx.x * EPB;

    for (int i = tid; i < NBUCK; i += 256) lh[i] = 0;
    __syncthreads();
    for (int i = tid; i < EPB; i += 256)
        atomicAdd(&lh[srcE[base + i] >> 6], 1);
    __syncthreads();
    for (int i = tid; i < NBUCK; i += 256) {
        const int c = lh[i];
        if (c) lbase[i] = atomicAdd(&cursor[i], c);
        lh[i] = 0;                      // reuse as local cursor
    }
    __syncthreads();
    for (int i = tid; i < EPB; i += 256) {
        const int e = base + i;
        const int s = srcE[e];
        const int d = dstE[e];
        const int b = s >> 6;
        const int loc = atomicAdd(&lh[b], 1);
        const int p = lbase[b] + loc;
        ss[p] = s; sd[p] = d; si[p] = e;
    }
}

// ---------------- edge pass (sorted, contiguous, XCD-chunked) --------------
// U' layout: within each 32-col block, c'' = l15*2+nt holds n'' = nt*16+l15.
// 16-lane group handles 8 consecutive 4-edge chunks (32 sorted edges).
// Blocks xcd_chunk-swizzled: contiguous sorted ranges stay on one XCD ->
// each bucket's 32 KB Us window is fetched once into that XCD's L2.
__global__ __launch_bounds__(256) void edge_score_sorted(
    const unsigned short* __restrict__ Us,
    const unsigned short* __restrict__ Ud,
    const int* __restrict__ ss,
    const int* __restrict__ sd,
    const int* __restrict__ si,
    const float* __restrict__ w2,
    const float* __restrict__ b2p,
    float* __restrict__ out)
{
    const int b = xcd_chunk(blockIdx.x, gridDim.x);
    const int tid = threadIdx.x;
    const int l = tid & 15;
    const int grp = b * 16 + (tid >> 4);   // 0..49999

    float w2v[16];
#pragma unroll
    for (int j = 0; j < 16; ++j) {
        const int cp = l * 16 + j;
        const int n = (cp & ~31) + ((cp & 1) << 4) + ((cp & 31) >> 1);
        w2v[j] = w2[n];
    }
    const float b2 = *b2p;

    const int g0 = grp * 8;
    for (int g = g0; g < g0 + 8; ++g) {
        const int e0 = g * 4;
        const int4 s4 = *(const int4*)(ss + e0);
        const int4 d4 = *(const int4*)(sd + e0);
        const int4 i4 = *(const int4*)(si + e0);
        const int sv[4] = {s4.x, s4.y, s4.z, s4.w};
        const int dv[4] = {d4.x, d4.y, d4.z, d4.w};

        bf16x8 u[4][2], v[4][2];
#pragma unroll
        for (int k = 0; k < 4; ++k) {
            const bf16x8* us = (const bf16x8*)(Us + (size_t)sv[k] * H + l * 16);
            const bf16x8* ud = (const bf16x8*)(Ud + (size_t)dv[k] * H + l * 16);
            u[k][0] = us[0]; u[k][1] = us[1];
            v[k][0] = ud[0]; v[k][1] = ud[1];
        }

        float4 res;
        float* resp = (float*)&res;
#pragma unroll
        for (int k = 0; k < 4; ++k) {
            float acc = 0.f;
#pragma unroll
            for (int j = 0; j < 8; ++j) {
                float hv = bf2f((unsigned short)u[k][0][j]) + bf2f((unsigned short)v[k][0][j]);
                acc = fmaf(fmaxf(hv, 0.f), w2v[j], acc);
            }
#pragma unroll
            for (int j = 0; j < 8; ++j) {
                float hv = bf2f((unsigned short)u[k][1][j]) + bf2f((unsigned short)v[k][1][j]);
                acc = fmaf(fmaxf(hv, 0.f), w2v[j + 8], acc);
            }
            acc += __shfl_xor(acc, 1, 16);
            acc += __shfl_xor(acc, 2, 16);
            acc += __shfl_xor(acc, 4, 16);
            acc += __shfl_xor(acc, 8, 16);
            resp[k] = acc + b2;
        }
        if (l == 0) {
            out[i4.x] = res.x;
            out[i4.y] = res.y;
            out[i4.z] = res.z;
            out[i4.w] = res.w;
        }
    }
}

// ---------------- edge pass (R12 unsorted, mid-ws fallback) ----------------
__global__ __launch_bounds__(256) void edge_score(
    const unsigned short* __restrict__ Us,
    const unsigned short* __restrict__ Ud,
    const int* __restrict__ srcE,
    const int* __restrict__ dstE,
    const float* __restrict__ w2,
    const float* __restrict__ b2p,
    float* __restrict__ out)
{
    const int gt = blockIdx.x * 256 + threadIdx.x;
    const int l = gt & 15;
    const int q = gt >> 4;
    const int Q = (gridDim.x * 256) >> 4;
    const int NGRP = E_TOTAL / 4;   // 400000

    float w2v[16];
#pragma unroll
    for (int j = 0; j < 16; ++j) {
        const int cp = l * 16 + j;
        const int n = (cp & ~31) + ((cp & 1) << 4) + ((cp & 31) >> 1);
        w2v[j] = w2[n];
    }
    const float b2 = *b2p;

    for (int g = q; g < NGRP; g += Q) {
        const int e0 = g * 4;
        const int4 s4 = *(const int4*)(srcE + e0);
        const int4 d4 = *(const int4*)(dstE + e0);
        const int sv[4] = {s4.x, s4.y, s4.z, s4.w};
        const int dv[4] = {d4.x, d4.y, d4.z, d4.w};

        bf16x8 u[4][2], v[4][2];
#pragma unroll
        for (int k = 0; k < 4; ++k) {
            const bf16x8* us = (const bf16x8*)(Us + (size_t)sv[k] * H + l * 16);
            const bf16x8* ud = (const bf16x8*)(Ud + (size_t)dv[k] * H + l * 16);
            u[k][0] = us[0]; u[k][1] = us[1];
            v[k][0] = ud[0]; v[k][1] = ud[1];
        }

        float4 res;
        float* resp = (float*)&res;
#pragma unroll
        for (int k = 0; k < 4; ++k) {
            float acc = 0.f;
#pragma unroll
            for (int j = 0; j < 8; ++j) {
                float hv = bf2f((unsigned short)u[k][0][j]) + bf2f((unsigned short)v[k][0][j]);
                acc = fmaf(fmaxf(hv, 0.f), w2v[j], acc);
            }
#pragma unroll
            for (int j = 0; j < 8; ++j) {
                float hv = bf2f((unsigned short)u[k][1][j]) + bf2f((unsigned short)v[k][1][j]);
                acc = fmaf(fmaxf(hv, 0.f), w2v[j + 8], acc);
            }
            acc += __shfl_xor(acc, 1, 16);
            acc += __shfl_xor(acc, 2, 16);
            acc += __shfl_xor(acc, 4, 16);
            acc += __shfl_xor(acc, 8, 16);
            resp[k] = acc + b2;
        }
        if (l == 0) *(float4*)(out + e0) = res;
    }
}

// ======================= R4 fallback (ws too small) ======================

#define TILE_M 32
#define NTILES (E_TOTAL / TILE_M)
#define GRID 2500

#if defined(__has_attribute)
#if __has_attribute(amdgpu_waves_per_eu)
#define LB __launch_bounds__(256) __attribute__((amdgpu_waves_per_eu(2, 2)))
#else
#define LB __launch_bounds__(256, 2)
#endif
#else
#define LB __launch_bounds__(256, 2)
#endif

__global__ LB void edge_mlp(
    const unsigned short* __restrict__ hbf,
    const int* __restrict__ srcE,
    const int* __restrict__ dstE,
    const unsigned short* __restrict__ w1bf,
    const float* __restrict__ b1,
    const float* __restrict__ w2,
    const float* __restrict__ b2p,
    float* __restrict__ out)
{
    __shared__ __align__(16) unsigned short X[2][TILE_M * K2];
    __shared__ float red[2][TILE_M][5];

    const int tid = threadIdx.x;
    const int wave = tid >> 6;
    const int lane = tid & 63;
    const int lane15 = lane & 15;
    const int quad = lane >> 4;

    bf16x8 B[8][4];
#pragma unroll
    for (int kit = 0; kit < 8; ++kit)
#pragma unroll
        for (int nt = 0; nt < 4; ++nt) {
            int n = wave * 64 + nt * 16 + lane15;
            int k = kit * 32 + quad * 8;
            B[kit][nt] = *(const bf16x8*)(w1bf + n * K2 + k);
        }

    float b1v[4], w2v[4];
#pragma unroll
    for (int nt = 0; nt < 4; ++nt) {
        int n = wave * 64 + nt * 16 + lane15;
        b1v[nt] = b1[n];
        w2v[nt] = w2[n];
    }
    const float b2 = *b2p;

    const int r_off = tid >> 5;
    const int c = (tid & 31) ^ (r_off & 7);
    const int half = c >> 4;
    const int fc = c & 15;
    const int* idx_base = half ? dstE : srcE;
    const int gshort = fc * 8;

    const int t0 = blockIdx.x;
    int inode[4];

#pragma unroll
    for (int it = 0; it < 4; ++it)
        inode[it] = idx_base[t0 * TILE_M + it * 8 + r_off];
#pragma unroll
    for (int it = 0; it < 4; ++it)
        __builtin_amdgcn_global_load_lds(
            (gas_t)(hbf + inode[it] * D + gshort),
            (las_t)(&X[0][0] + it * 2048 + wave * 512), 16, 0, 0);
    {
        const int t1 = t0 + GRID;
#pragma unroll
        for (int it = 0; it < 4; ++it)
            inode[it] = idx_base[t1 * TILE_M + it * 8 + r_off];
    }

    int buf = 0;
    int prev_eb = -1;

    for (int tile = t0; tile < NTILES; tile += GRID) {
        __syncthreads();

        const int nt1 = tile + GRID;
        if (nt1 < NTILES) {
            unsigned short* Xn = &X[buf ^ 1][0];
#pragma unroll
            for (int it = 0; it < 4; ++it)
                __builtin_amdgcn_global_load_lds(
                    (gas_t)(hbf + inode[it] * D + gshort),
                    (las_t)(Xn + it * 2048 + wave * 512), 16, 0, 0);
        }
        const int nt2 = tile + 2 * GRID;
        if (nt2 < NTILES) {
            const int eb2 = nt2 * TILE_M;
#pragma unroll
            for (int it = 0; it < 4; ++it)
                inode[it] = idx_base[eb2 + it * 8 + r_off];
        }
        if (prev_eb >= 0 && tid < TILE_M) {
            float s = b2;
#pragma unroll
            for (int w = 0; w < 4; ++w) s += red[buf ^ 1][tid][w];
            out[prev_eb + tid] = s;
        }

        const unsigned short* Xc = &X[buf][0];
        f32x4 acc[2][4];
        const f32x4 zero = {0.f, 0.f, 0.f, 0.f};
#pragma unroll
        for (int ms = 0; ms < 2; ++ms)
#pragma unroll
            for (int nt = 0; nt < 4; ++nt)
                acc[ms][nt] = zero;

#pragma unroll
        for (int kit = 0; kit < 8; ++kit) {
            const int p8 = (((kit * 4 + quad) ^ (lane15 & 7))) * 8;
            bf16x8 a[2];
#pragma unroll
            for (int ms = 0; ms < 2; ++ms)
                a[ms] = *(const bf16x8*)&Xc[(ms * 16 + lane15) * K2 + p8];
#pragma unroll
            for (int ms = 0; ms < 2; ++ms)
#pragma unroll
                for (int nt = 0; nt < 4; ++nt)
                    acc[ms][nt] = __builtin_amdgcn_mfma_f32_16x16x32_bf16(
                        a[ms], B[kit][nt], acc[ms][nt], 0, 0, 0);
        }

#pragma unroll
        for (int ms = 0; ms < 2; ++ms)
#pragma unroll
            for (int r = 0; r < 4; ++r) {
                float p = 0.f;
#pragma unroll
                for (int nt = 0; nt < 4; ++nt) {
                    float hv = acc[ms][nt][r] + b1v[nt];
                    p = fmaf(fmaxf(hv, 0.f), w2v[nt], p);
                }
                p += __shfl_xor(p, 1, 16);
                p += __shfl_xor(p, 2, 16);
                p += __shfl_xor(p, 4, 16);
                p += __shfl_xor(p, 8, 16);
                if (lane15 == 0) red[buf][ms * 16 + quad * 4 + r][wave] = p;
            }
        prev_eb = tile * TILE_M;
        buf ^= 1;
    }

    __syncthreads();
    if (prev_eb >= 0 && tid < TILE_M) {
        float s = b2;
#pragma unroll
        for (int w = 0; w < 4; ++w) s += red[buf ^ 1][tid][w];
        out[prev_eb + tid] = s;
    }
}

// ================================ launch ================================

extern "C" void kernel_launch(void* const* d_in, const int* in_sizes, int n_in,
                              void* d_out, int out_size, void* d_ws, size_t ws_size,
                              hipStream_t stream) {
    const float* h    = (const float*)d_in[0];
    const int*   srcE = (const int*)d_in[1];
    const int*   dstE = (const int*)d_in[2];
    const float* W1   = (const float*)d_in[3];
    const float* b1   = (const float*)d_in[4];
    const float* w2   = (const float*)d_in[5];
    const float* b2   = (const float*)d_in[6];
    float* out = (float*)d_out;

    char* ws = (char*)d_ws;
    const size_t offUs   = 0;                        // 51,200,000 B
    const size_t offUd   = 51200000;                 // 51,200,000 B
    const size_t offHbf  = 102400000;                // 25,600,000 B
    const size_t offW1bf = 128000000;                // 131,072 B
    const size_t need    = offW1bf + 131072;         // 128,131,072 B
    // sort extras
    const size_t offHist = need;                     // 8,192 B (1563 ints)
    const size_t offCur  = offHist + 8192;           // 8,192 B
    const size_t offSS   = offCur + 8192;            // 6,400,000 B
    const size_t offSD   = offSS + 6400000;          // 6,400,000 B
    const size_t offSI   = offSD + 6400000;          // 6,400,000 B
    const size_t need2   = offSI + 6400000;          // 147,347,456 B

    if (ws_size >= need) {
        unsigned short* Us   = (unsigned short*)(ws + offUs);
        unsigned short* Ud   = (unsigned short*)(ws + offUd);
        unsigned short* hbf  = (unsigned short*)(ws + offHbf);
        unsigned short* w1bf = (unsigned short*)(ws + offW1bf);
        const bool sorted = (ws_size >= need2);
        int* hist = (int*)(ws + offHist);
        int* cur  = (int*)(ws + offCur);
        int* ss   = (int*)(ws + offSS);
        int* sd   = (int*)(ws + offSD);
        int* si   = (int*)(ws + offSI);

        int n4h = NNODES * D / 4, n4w = H * K2 / 4;
        const int nz = sorted ? NBUCK : 0;
        cvt_kernel<<<(n4h + n4w + nz + 255) / 256, 256, 0, stream>>>(
            h, W1, hbf, w1bf, n4h, n4w, hist, nz);
        u_gemm3<<<4 * ((NNODES + 63) / 64), 256, 0, stream>>>(hbf, w1bf, b1, Us, Ud);
        if (sorted) {
            hist_kernel<<<SORT_GRID, 256, 0, stream>>>(srcE, hist);
            scan_kernel<<<1, 256, 0, stream>>>(hist, cur);
            scatter3<<<SORT_GRID, 256, 0, stream>>>(srcE, dstE, cur, ss, sd, si);
            edge_score_sorted<<<EDGE_GRID, 256, 0, stream>>>(Us, Ud, ss, sd, si, w2, b2, out);
        } else {
            edge_score<<<4096, 256, 0, stream>>>(Us, Ud, srcE, dstE, w2, b2, out);
        }
    } else {
        unsigned short* hbf  = (unsigned short*)d_ws;
        unsigned short* w1bf = hbf + (size_t)NNODES * D;
        int n4h = NNODES * D / 4, n4w = H * K2 / 4;
        cvt_kernel<<<(n4h + n4w + 255) / 256, 256, 0, stream>>>(
            h, W1, hbf, w1bf, n4h, n4w, nullptr, 0);
        edge_mlp<<<GRID, 256, 0, stream>>>(hbf, srcE, dstE, w1bf, b1, w2, b2, out);
    }
}

// Round 5
// 347.111 us; speedup vs baseline: 2.2223x; 1.2400x over previous
//
#include <hip/hip_runtime.h>

// LinkPredictor: score[e] = w2 . relu(W1 . concat(h[src[e]], h[dst[e]]) + b1) + b2
// N_NODES=100000, N_EDGES=1600000, D=128, HIDDEN=256
//
// R17: coarse radix-49 sort (bucket = 2048 src nodes = 1 MB Us window).
//   R16 post-mortem: sort DID cut edge traffic (774->597 MB, 225->185 us,
//   rate pinned at 3.59 TB/s -> time = traffic/3.5 model confirmed), but
//   scatter3's 64-node buckets scattered 48 B runs into 1563 ranges ->
//   ~95 us of write-amplified sort. L2 is 4 MB/XCD: Us window only needs
//   <= ~1-2 MB, so 49 buckets suffice -> per-(block,bucket) runs ~1 KB,
//   fully coalesced. hist does range-reserve; 49-prefix recomputed inline
//   per scatter block (no scan dispatch). Edge packed to ONE uint64
//   (src:17|dst:17|idx:21). Chain = 5 dispatches.
//   Predict: hist+scatter ~15 us, edge FETCH ~540 MB dur ~160 us,
//   total ~315-335 us. If >= 360: revert to R12, declare pattern ceiling.

#define NNODES 100000
#define E_TOTAL 1600000
#define D 128
#define K2 256
#define H 256
#define NB2 49                       // ceil(100000/2048) coarse src buckets
#define EDGE_GRID 3125               // 3125 blk * 16 grp * 8 chunks * 4 edges = 1.6M
#define SORT_GRID 256                // hist/scatter blocks
#define EPB (E_TOTAL / SORT_GRID)    // 6250 edges per sort block

typedef short bf16x8 __attribute__((ext_vector_type(8)));
typedef float f32x4 __attribute__((ext_vector_type(4)));
typedef const __attribute__((address_space(1))) unsigned short* gas_t;
typedef __attribute__((address_space(3))) unsigned short* las_t;

__device__ __forceinline__ unsigned short f2bf(float f) {
    unsigned u = __float_as_uint(f);
    u += 0x7fff + ((u >> 16) & 1);   // round-to-nearest-even
    return (unsigned short)(u >> 16);
}
__device__ __forceinline__ float bf2f(unsigned short s) {
    return __uint_as_float((unsigned)s << 16);
}

// m204 bijective chunked XCD swizzle: consecutive output ids -> same XCD.
__device__ __forceinline__ int xcd_chunk(int orig, int nwg) {
    const int q = nwg >> 3, r = nwg & 7;
    const int x = orig & 7, s = orig >> 3;
    return (x < r ? x * (q + 1) : r * (q + 1) + (x - r) * q) + s;
}

// ---------------- cvt: h and W1 -> bf16 (+ gh zero fused) ----------------
__global__ void cvt_kernel(const float* __restrict__ h, const float* __restrict__ w1,
                           unsigned short* __restrict__ hbf, unsigned short* __restrict__ w1bf,
                           int n4h, int n4w, int* __restrict__ gh, int nz) {
    int i = blockIdx.x * blockDim.x + threadIdx.x;
    if (i >= n4h + n4w) {
        int z = i - (n4h + n4w);
        if (z < nz) gh[z] = 0;
        return;
    }
    const float* s; unsigned short* d; int j;
    if (i < n4h) { s = h; d = hbf; j = i; }
    else { s = w1; d = w1bf; j = i - n4h; }
    float4 v = ((const float4*)s)[j];
    ushort4 o;
    o.x = f2bf(v.x); o.y = f2bf(v.y); o.z = f2bf(v.z); o.w = f2bf(v.w);
    ((ushort4*)d)[j] = o;
}

// ---------------- u_gemm v3 (R12 form) ----------------
// blockIdx bx: tile = bx>>2 (64 node rows), half = (bx>>1)&1 (0: Us + b1 fold,
// 1: Ud), nh = bx&1 (cols 0-127 vs 128-255 of the half's output).
__global__ __launch_bounds__(256, 4) void u_gemm3(
    const unsigned short* __restrict__ hbf,
    const unsigned short* __restrict__ w1bf,
    const float* __restrict__ b1,
    unsigned short* __restrict__ Us,
    unsigned short* __restrict__ Ud)
{
    __shared__ __align__(16) unsigned short A[64 * 128];   // 16384 B

    const int tid = threadIdx.x;
    const int wave = tid >> 6;
    const int lane = tid & 63;
    const int l15 = lane & 15;
    const int quad = lane >> 4;

    const int tile = blockIdx.x >> 2;
    const int half = (blockIdx.x >> 1) & 1;
    const int nh = blockIdx.x & 1;
    const int r0 = tile * 64;
    int rows = NNODES - r0; if (rows > 64) rows = 64;
    const int koff = half * 128;
    unsigned short* U = half ? Ud : Us;

    // --- issue async stage of A (16 KB), XOR swizzle c = p ^ (r&15) ---
#pragma unroll
    for (int it = 0; it < 4; ++it) {
        const int s = it * 256 + tid;      // 16B slot 0..1023
        const int r = s >> 4;              // row 0..63
        const int p = s & 15;              // position chunk
        const int c = p ^ (r & 15);        // content chunk
        if (r < rows)
            __builtin_amdgcn_global_load_lds(
                (gas_t)(hbf + (size_t)(r0 + r) * D + c * 8),
                (las_t)(A + it * 2048 + wave * 512), 16, 0, 0);
    }

    // --- B fragments + bias while DMA is in flight ---
    bf16x8 B[4][2];
    float bias[2];
#pragma unroll
    for (int nt = 0; nt < 2; ++nt) {
        const int n = nh * 128 + wave * 32 + nt * 16 + l15;
        bias[nt] = half ? 0.f : b1[n];
#pragma unroll
        for (int kit = 0; kit < 4; ++kit)
            B[kit][nt] = *(const bf16x8*)(w1bf + (size_t)n * K2 + koff + kit * 32 + quad * 8);
    }

    __syncthreads();   // vmcnt(0): A landed

    f32x4 acc[4][2];
    const f32x4 zero = {0.f, 0.f, 0.f, 0.f};
#pragma unroll
    for (int ms = 0; ms < 4; ++ms)
#pragma unroll
        for (int nt = 0; nt < 2; ++nt)
            acc[ms][nt] = zero;

#pragma unroll
    for (int kit = 0; kit < 4; ++kit) {
        bf16x8 a[4];
#pragma unroll
        for (int ms = 0; ms < 4; ++ms) {
            const int row = ms * 16 + l15;
            const int p = (kit * 4 + quad) ^ l15;
            a[ms] = *(const bf16x8*)&A[row * 128 + p * 8];
        }
#pragma unroll
        for (int ms = 0; ms < 4; ++ms)
#pragma unroll
            for (int nt = 0; nt < 2; ++nt)
                acc[ms][nt] = __builtin_amdgcn_mfma_f32_16x16x32_bf16(
                    a[ms], B[kit][nt], acc[ms][nt], 0, 0, 0);
    }

    // --- direct permuted store: dword per (ms,r), 64B segment per quad ---
    const int coff = nh * 128 + wave * 32 + l15 * 2;   // short offset in U row
#pragma unroll
    for (int ms = 0; ms < 4; ++ms) {
#pragma unroll
        for (int r = 0; r < 4; ++r) {
            const int m = ms * 16 + quad * 4 + r;
            if (m < rows) {
                const unsigned lo = f2bf(acc[ms][0][r] + bias[0]);
                const unsigned hi = f2bf(acc[ms][1][r] + bias[1]);
                *(unsigned*)(U + (size_t)(r0 + m) * H + coff) = lo | (hi << 16);
            }
        }
    }
}

// ---------------- hist49: count + per-block range reservation --------------
// 256 blocks x 6250 edges. LDS count over 49 buckets; one atomicAdd per
// (block,bucket) reserves this block's slice within the bucket (12.5K total).
__global__ __launch_bounds__(256) void hist49(
    const int* __restrict__ srcE, int* __restrict__ gh, int* __restrict__ bOff)
{
    __shared__ int lh[NB2];
    const int tid = threadIdx.x;
    const int base = blockIdx.x * EPB;
    if (tid < NB2) lh[tid] = 0;
    __syncthreads();
    for (int i = tid; i < EPB; i += 256)
        atomicAdd(&lh[srcE[base + i] >> 11], 1);
    __syncthreads();
    if (tid < NB2)
        bOff[blockIdx.x * NB2 + tid] = atomicAdd(&gh[tid], lh[tid]);
}

// ---------------- scatter49: coalesced packed scatter ----------------------
// Each block recomputes the 49-prefix from gh (complete after hist49),
// then scatters its edges as uint64 (src:17 | dst:17 | idx:21) into
// pos = prefix[b] + bOff[blk][b] + localrank. Runs avg ~1 KB -> coalesced.
__global__ __launch_bounds__(256) void scatter49(
    const int* __restrict__ srcE, const int* __restrict__ dstE,
    const int* __restrict__ gh, const int* __restrict__ bOff,
    unsigned long long* __restrict__ pk)
{
    __shared__ int pref[NB2];
    __shared__ int lcur[NB2];
    const int tid = threadIdx.x;
    const int base = blockIdx.x * EPB;
    if (tid == 0) {
        int s = 0;
        for (int b = 0; b < NB2; ++b) { pref[b] = s; s += gh[b]; }
    }
    if (tid < NB2) lcur[tid] = bOff[blockIdx.x * NB2 + tid];
    __syncthreads();
    for (int i = tid; i < EPB; i += 256) {
        const int e = base + i;
        const int s = srcE[e];
        const int d = dstE[e];
        const int b = s >> 11;
        const int r = atomicAdd(&lcur[b], 1);
        pk[(size_t)(pref[b] + r)] =
            (unsigned long long)s | ((unsigned long long)d << 17) |
            ((unsigned long long)e << 34);
    }
}

// ---------------- edge pass (sorted packed, XCD-chunked) -------------------
// U' layout: within each 32-col block, c'' = l15*2+nt holds n'' = nt*16+l15.
// 16-lane group handles 8 consecutive 4-edge chunks (32 sorted edges).
// Blocks xcd_chunk-swizzled: contiguous sorted ranges stay on one XCD ->
// each 1 MB src-bucket Us window is fetched ~once into that XCD's L2.
__global__ __launch_bounds__(256) void edge_score_pk(
    const unsigned short* __restrict__ Us,
    const unsigned short* __restrict__ Ud,
    const unsigned long long* __restrict__ pk,
    const float* __restrict__ w2,
    const float* __restrict__ b2p,
    float* __restrict__ out)
{
    const int b = xcd_chunk(blockIdx.x, gridDim.x);
    const int tid = threadIdx.x;
    const int l = tid & 15;
    const int grp = b * 16 + (tid >> 4);   // 0..49999

    float w2v[16];
#pragma unroll
    for (int j = 0; j < 16; ++j) {
        const int cp = l * 16 + j;
        const int n = (cp & ~31) + ((cp & 1) << 4) + ((cp & 31) >> 1);
        w2v[j] = w2[n];
    }
    const float b2 = *b2p;

    const int g0 = grp * 8;
    for (int g = g0; g < g0 + 8; ++g) {
        const int e0 = g * 4;
        const uint4 pa = *(const uint4*)(pk + e0);       // edges 0,1
        const uint4 pb = *(const uint4*)(pk + e0 + 2);   // edges 2,3
        const unsigned lo[4] = {pa.x, pa.z, pb.x, pb.z};
        const unsigned hi[4] = {pa.y, pa.w, pb.y, pb.w};
        int sv[4], dv[4], ev[4];
#pragma unroll
        for (int k = 0; k < 4; ++k) {
            sv[k] = lo[k] & 0x1FFFF;
            dv[k] = ((lo[k] >> 17) | (hi[k] << 15)) & 0x1FFFF;
            ev[k] = hi[k] >> 2;
        }

        bf16x8 u[4][2], v[4][2];
#pragma unroll
        for (int k = 0; k < 4; ++k) {
            const bf16x8* us = (const bf16x8*)(Us + (size_t)sv[k] * H + l * 16);
            const bf16x8* ud = (const bf16x8*)(Ud + (size_t)dv[k] * H + l * 16);
            u[k][0] = us[0]; u[k][1] = us[1];
            v[k][0] = ud[0]; v[k][1] = ud[1];
        }

        float res[4];
#pragma unroll
        for (int k = 0; k < 4; ++k) {
            float acc = 0.f;
#pragma unroll
            for (int j = 0; j < 8; ++j) {
                float hv = bf2f((unsigned short)u[k][0][j]) + bf2f((unsigned short)v[k][0][j]);
                acc = fmaf(fmaxf(hv, 0.f), w2v[j], acc);
            }
#pragma unroll
            for (int j = 0; j < 8; ++j) {
                float hv = bf2f((unsigned short)u[k][1][j]) + bf2f((unsigned short)v[k][1][j]);
                acc = fmaf(fmaxf(hv, 0.f), w2v[j + 8], acc);
            }
            acc += __shfl_xor(acc, 1, 16);
            acc += __shfl_xor(acc, 2, 16);
            acc += __shfl_xor(acc, 4, 16);
            acc += __shfl_xor(acc, 8, 16);
            res[k] = acc + b2;
        }
        if (l == 0) {
            out[ev[0]] = res[0];
            out[ev[1]] = res[1];
            out[ev[2]] = res[2];
            out[ev[3]] = res[3];
        }
    }
}

// ---------------- edge pass (R12 unsorted, mid-ws fallback) ----------------
__global__ __launch_bounds__(256) void edge_score(
    const unsigned short* __restrict__ Us,
    const unsigned short* __restrict__ Ud,
    const int* __restrict__ srcE,
    const int* __restrict__ dstE,
    const float* __restrict__ w2,
    const float* __restrict__ b2p,
    float* __restrict__ out)
{
    const int gt = blockIdx.x * 256 + threadIdx.x;
    const int l = gt & 15;
    const int q = gt >> 4;
    const int Q = (gridDim.x * 256) >> 4;
    const int NGRP = E_TOTAL / 4;   // 400000

    float w2v[16];
#pragma unroll
    for (int j = 0; j < 16; ++j) {
        const int cp = l * 16 + j;
        const int n = (cp & ~31) + ((cp & 1) << 4) + ((cp & 31) >> 1);
        w2v[j] = w2[n];
    }
    const float b2 = *b2p;

    for (int g = q; g < NGRP; g += Q) {
        const int e0 = g * 4;
        const int4 s4 = *(const int4*)(srcE + e0);
        const int4 d4 = *(const int4*)(dstE + e0);
        const int sv[4] = {s4.x, s4.y, s4.z, s4.w};
        const int dv[4] = {d4.x, d4.y, d4.z, d4.w};

        bf16x8 u[4][2], v[4][2];
#pragma unroll
        for (int k = 0; k < 4; ++k) {
            const bf16x8* us = (const bf16x8*)(Us + (size_t)sv[k] * H + l * 16);
            const bf16x8* ud = (const bf16x8*)(Ud + (size_t)dv[k] * H + l * 16);
            u[k][0] = us[0]; u[k][1] = us[1];
            v[k][0] = ud[0]; v[k][1] = ud[1];
        }

        float4 res;
        float* resp = (float*)&res;
#pragma unroll
        for (int k = 0; k < 4; ++k) {
            float acc = 0.f;
#pragma unroll
            for (int j = 0; j < 8; ++j) {
                float hv = bf2f((unsigned short)u[k][0][j]) + bf2f((unsigned short)v[k][0][j]);
                acc = fmaf(fmaxf(hv, 0.f), w2v[j], acc);
            }
#pragma unroll
            for (int j = 0; j < 8; ++j) {
                float hv = bf2f((unsigned short)u[k][1][j]) + bf2f((unsigned short)v[k][1][j]);
                acc = fmaf(fmaxf(hv, 0.f), w2v[j + 8], acc);
            }
            acc += __shfl_xor(acc, 1, 16);
            acc += __shfl_xor(acc, 2, 16);
            acc += __shfl_xor(acc, 4, 16);
            acc += __shfl_xor(acc, 8, 16);
            resp[k] = acc + b2;
        }
        if (l == 0) *(float4*)(out + e0) = res;
    }
}

// ======================= R4 fallback (ws too small) ======================

#define TILE_M 32
#define NTILES (E_TOTAL / TILE_M)
#define GRID 2500

#if defined(__has_attribute)
#if __has_attribute(amdgpu_waves_per_eu)
#define LB __launch_bounds__(256) __attribute__((amdgpu_waves_per_eu(2, 2)))
#else
#define LB __launch_bounds__(256, 2)
#endif
#else
#define LB __launch_bounds__(256, 2)
#endif

__global__ LB void edge_mlp(
    const unsigned short* __restrict__ hbf,
    const int* __restrict__ srcE,
    const int* __restrict__ dstE,
    const unsigned short* __restrict__ w1bf,
    const float* __restrict__ b1,
    const float* __restrict__ w2,
    const float* __restrict__ b2p,
    float* __restrict__ out)
{
    __shared__ __align__(16) unsigned short X[2][TILE_M * K2];
    __shared__ float red[2][TILE_M][5];

    const int tid = threadIdx.x;
    const int wave = tid >> 6;
    const int lane = tid & 63;
    const int lane15 = lane & 15;
    const int quad = lane >> 4;

    bf16x8 B[8][4];
#pragma unroll
    for (int kit = 0; kit < 8; ++kit)
#pragma unroll
        for (int nt = 0; nt < 4; ++nt) {
            int n = wave * 64 + nt * 16 + lane15;
            int k = kit * 32 + quad * 8;
            B[kit][nt] = *(const bf16x8*)(w1bf + n * K2 + k);
        }

    float b1v[4], w2v[4];
#pragma unroll
    for (int nt = 0; nt < 4; ++nt) {
        int n = wave * 64 + nt * 16 + lane15;
        b1v[nt] = b1[n];
        w2v[nt] = w2[n];
    }
    const float b2 = *b2p;

    const int r_off = tid >> 5;
    const int c = (tid & 31) ^ (r_off & 7);
    const int half = c >> 4;
    const int fc = c & 15;
    const int* idx_base = half ? dstE : srcE;
    const int gshort = fc * 8;

    const int t0 = blockIdx.x;
    int inode[4];

#pragma unroll
    for (int it = 0; it < 4; ++it)
        inode[it] = idx_base[t0 * TILE_M + it * 8 + r_off];
#pragma unroll
    for (int it = 0; it < 4; ++it)
        __builtin_amdgcn_global_load_lds(
            (gas_t)(hbf + inode[it] * D + gshort),
            (las_t)(&X[0][0] + it * 2048 + wave * 512), 16, 0, 0);
    {
        const int t1 = t0 + GRID;
#pragma unroll
        for (int it = 0; it < 4; ++it)
            inode[it] = idx_base[t1 * TILE_M + it * 8 + r_off];
    }

    int buf = 0;
    int prev_eb = -1;

    for (int tile = t0; tile < NTILES; tile += GRID) {
        __syncthreads();

        const int nt1 = tile + GRID;
        if (nt1 < NTILES) {
            unsigned short* Xn = &X[buf ^ 1][0];
#pragma unroll
            for (int it = 0; it < 4; ++it)
                __builtin_amdgcn_global_load_lds(
                    (gas_t)(hbf + inode[it] * D + gshort),
                    (las_t)(Xn + it * 2048 + wave * 512), 16, 0, 0);
        }
        const int nt2 = tile + 2 * GRID;
        if (nt2 < NTILES) {
            const int eb2 = nt2 * TILE_M;
#pragma unroll
            for (int it = 0; it < 4; ++it)
                inode[it] = idx_base[eb2 + it * 8 + r_off];
        }
        if (prev_eb >= 0 && tid < TILE_M) {
            float s = b2;
#pragma unroll
            for (int w = 0; w < 4; ++w) s += red[buf ^ 1][tid][w];
            out[prev_eb + tid] = s;
        }

        const unsigned short* Xc = &X[buf][0];
        f32x4 acc[2][4];
        const f32x4 zero = {0.f, 0.f, 0.f, 0.f};
#pragma unroll
        for (int ms = 0; ms < 2; ++ms)
#pragma unroll
            for (int nt = 0; nt < 4; ++nt)
                acc[ms][nt] = zero;

#pragma unroll
        for (int kit = 0; kit < 8; ++kit) {
            const int p8 = (((kit * 4 + quad) ^ (lane15 & 7))) * 8;
            bf16x8 a[2];
#pragma unroll
            for (int ms = 0; ms < 2; ++ms)
                a[ms] = *(const bf16x8*)&Xc[(ms * 16 + lane15) * K2 + p8];
#pragma unroll
            for (int ms = 0; ms < 2; ++ms)
#pragma unroll
                for (int nt = 0; nt < 4; ++nt)
                    acc[ms][nt] = __builtin_amdgcn_mfma_f32_16x16x32_bf16(
                        a[ms], B[kit][nt], acc[ms][nt], 0, 0, 0);
        }

#pragma unroll
        for (int ms = 0; ms < 2; ++ms)
#pragma unroll
            for (int r = 0; r < 4; ++r) {
                float p = 0.f;
#pragma unroll
                for (int nt = 0; nt < 4; ++nt) {
                    float hv = acc[ms][nt][r] + b1v[nt];
                    p = fmaf(fmaxf(hv, 0.f), w2v[nt], p);
                }
                p += __shfl_xor(p, 1, 16);
                p += __shfl_xor(p, 2, 16);
                p += __shfl_xor(p, 4, 16);
                p += __shfl_xor(p, 8, 16);
                if (lane15 == 0) red[buf][ms * 16 + quad * 4 + r][wave] = p;
            }
        prev_eb = tile * TILE_M;
        buf ^= 1;
    }

    __syncthreads();
    if (prev_eb >= 0 && tid < TILE_M) {
        float s = b2;
#pragma unroll
        for (int w = 0; w < 4; ++w) s += red[buf ^ 1][tid][w];
        out[prev_eb + tid] = s;
    }
}

// ================================ launch ================================

extern "C" void kernel_launch(void* const* d_in, const int* in_sizes, int n_in,
                              void* d_out, int out_size, void* d_ws, size_t ws_size,
                              hipStream_t stream) {
    const float* h    = (const float*)d_in[0];
    const int*   srcE = (const int*)d_in[1];
    const int*   dstE = (const int*)d_in[2];
    const float* W1   = (const float*)d_in[3];
    const float* b1   = (const float*)d_in[4];
    const float* w2   = (const float*)d_in[5];
    const float* b2   = (const float*)d_in[6];
    float* out = (float*)d_out;

    char* ws = (char*)d_ws;
    const size_t offUs   = 0;                        // 51,200,000 B
    const size_t offUd   = 51200000;                 // 51,200,000 B
    const size_t offHbf  = 102400000;                // 25,600,000 B
    const size_t offW1bf = 128000000;                // 131,072 B
    const size_t need    = offW1bf + 131072;         // 128,131,072 B
    // R17 sort extras
    const size_t offGh   = need;                     // 49 ints (pad 4096)
    const size_t offBO   = offGh + 4096;             // 256*49 ints (pad 65536)
    const size_t offPK   = offBO + 65536;            // 12,800,000 B (uint64/edge)
    const size_t need2   = offPK + 12800000;         // 141,000,704 B

    if (ws_size >= need) {
        unsigned short* Us   = (unsigned short*)(ws + offUs);
        unsigned short* Ud   = (unsigned short*)(ws + offUd);
        unsigned short* hbf  = (unsigned short*)(ws + offHbf);
        unsigned short* w1bf = (unsigned short*)(ws + offW1bf);
        const bool sorted = (ws_size >= need2);
        int* gh  = (int*)(ws + offGh);
        int* bO  = (int*)(ws + offBO);
        unsigned long long* pk = (unsigned long long*)(ws + offPK);

        int n4h = NNODES * D / 4, n4w = H * K2 / 4;
        const int nz = sorted ? NB2 : 0;
        cvt_kernel<<<(n4h + n4w + nz + 255) / 256, 256, 0, stream>>>(
            h, W1, hbf, w1bf, n4h, n4w, gh, nz);
        u_gemm3<<<4 * ((NNODES + 63) / 64), 256, 0, stream>>>(hbf, w1bf, b1, Us, Ud);
        if (sorted) {
            hist49<<<SORT_GRID, 256, 0, stream>>>(srcE, gh, bO);
            scatter49<<<SORT_GRID, 256, 0, stream>>>(srcE, dstE, gh, bO, pk);
            edge_score_pk<<<EDGE_GRID, 256, 0, stream>>>(Us, Ud, pk, w2, b2, out);
        } else {
            edge_score<<<4096, 256, 0, stream>>>(Us, Ud, srcE, dstE, w2, b2, out);
        }
    } else {
        unsigned short* hbf  = (unsigned short*)d_ws;
        unsigned short* w1bf = hbf + (size_t)NNODES * D;
        int n4h = NNODES * D / 4, n4w = H * K2 / 4;
        cvt_kernel<<<(n4h + n4w + 255) / 256, 256, 0, stream>>>(
            h, W1, hbf, w1bf, n4h, n4w, nullptr, 0);
        edge_mlp<<<GRID, 256, 0, stream>>>(hbf, srcE, dstE, w1bf, b1, w2, b2, out);
    }
}

// Round 6
// 335.199 us; speedup vs baseline: 2.3013x; 1.0355x over previous
//
#include <hip/hip_runtime.h>

// LinkPredictor: score[e] = w2 . relu(W1 . concat(h[src[e]], h[dst[e]]) + b1) + b2
// N_NODES=100000, N_EDGES=1600000, D=128, HIDDEN=256
//
// R18: kill the output write-scatter (RFO traffic).
//   R17 post-mortem: edge FETCH 557 = Us 51 + pk 13 + Ud ~390 + ~100 MB RFO
//   from 1.6M scattered dword out-stores; WRITE 7->48 MB amplification
//   confirms (R12 coalesced float4 writes had neither). ~140 MB ~= 40 us
//   at the invariant ~3.5 TB/s L2-miss service rate.
//   Fix: edge kernel writes score_sorted[p] coalesced; scatter49 also emits
//   rank[e]=p (coalesced addr); new unscatter: out[e]=score_sorted[rank[e]]
//   (random READ over 6.4 MB - line-shared, no RFO - + coalesced write).
//   rank/score_sorted reuse the dead hbf region (hbf unused after u_gemm3).
//   Predict: edge FETCH ~455 WRITE ~7 dur ~132; unscatter ~10 us;
//   total 347 -> ~320 us. If edge FETCH stays ~557: RFO theory wrong, revert.

#define NNODES 100000
#define E_TOTAL 1600000
#define D 128
#define K2 256
#define H 256
#define NB2 49                       // ceil(100000/2048) coarse src buckets
#define EDGE_GRID 3125               // 3125 blk * 16 grp * 8 chunks * 4 edges = 1.6M
#define SORT_GRID 256                // hist/scatter blocks
#define EPB (E_TOTAL / SORT_GRID)    // 6250 edges per sort block

typedef short bf16x8 __attribute__((ext_vector_type(8)));
typedef float f32x4 __attribute__((ext_vector_type(4)));
typedef const __attribute__((address_space(1))) unsigned short* gas_t;
typedef __attribute__((address_space(3))) unsigned short* las_t;

__device__ __forceinline__ unsigned short f2bf(float f) {
    unsigned u = __float_as_uint(f);
    u += 0x7fff + ((u >> 16) & 1);   // round-to-nearest-even
    return (unsigned short)(u >> 16);
}
__device__ __forceinline__ float bf2f(unsigned short s) {
    return __uint_as_float((unsigned)s << 16);
}

// m204 bijective chunked XCD swizzle: consecutive output ids -> same XCD.
__device__ __forceinline__ int xcd_chunk(int orig, int nwg) {
    const int q = nwg >> 3, r = nwg & 7;
    const int x = orig & 7, s = orig >> 3;
    return (x < r ? x * (q + 1) : r * (q + 1) + (x - r) * q) + s;
}

// ---------------- cvt: h and W1 -> bf16 (+ gh zero fused) ----------------
__global__ void cvt_kernel(const float* __restrict__ h, const float* __restrict__ w1,
                           unsigned short* __restrict__ hbf, unsigned short* __restrict__ w1bf,
                           int n4h, int n4w, int* __restrict__ gh, int nz) {
    int i = blockIdx.x * blockDim.x + threadIdx.x;
    if (i >= n4h + n4w) {
        int z = i - (n4h + n4w);
        if (z < nz) gh[z] = 0;
        return;
    }
    const float* s; unsigned short* d; int j;
    if (i < n4h) { s = h; d = hbf; j = i; }
    else { s = w1; d = w1bf; j = i - n4h; }
    float4 v = ((const float4*)s)[j];
    ushort4 o;
    o.x = f2bf(v.x); o.y = f2bf(v.y); o.z = f2bf(v.z); o.w = f2bf(v.w);
    ((ushort4*)d)[j] = o;
}

// ---------------- u_gemm v3 (R12 form) ----------------
// blockIdx bx: tile = bx>>2 (64 node rows), half = (bx>>1)&1 (0: Us + b1 fold,
// 1: Ud), nh = bx&1 (cols 0-127 vs 128-255 of the half's output).
__global__ __launch_bounds__(256, 4) void u_gemm3(
    const unsigned short* __restrict__ hbf,
    const unsigned short* __restrict__ w1bf,
    const float* __restrict__ b1,
    unsigned short* __restrict__ Us,
    unsigned short* __restrict__ Ud)
{
    __shared__ __align__(16) unsigned short A[64 * 128];   // 16384 B

    const int tid = threadIdx.x;
    const int wave = tid >> 6;
    const int lane = tid & 63;
    const int l15 = lane & 15;
    const int quad = lane >> 4;

    const int tile = blockIdx.x >> 2;
    const int half = (blockIdx.x >> 1) & 1;
    const int nh = blockIdx.x & 1;
    const int r0 = tile * 64;
    int rows = NNODES - r0; if (rows > 64) rows = 64;
    const int koff = half * 128;
    unsigned short* U = half ? Ud : Us;

    // --- issue async stage of A (16 KB), XOR swizzle c = p ^ (r&15) ---
#pragma unroll
    for (int it = 0; it < 4; ++it) {
        const int s = it * 256 + tid;      // 16B slot 0..1023
        const int r = s >> 4;              // row 0..63
        const int p = s & 15;              // position chunk
        const int c = p ^ (r & 15);        // content chunk
        if (r < rows)
            __builtin_amdgcn_global_load_lds(
                (gas_t)(hbf + (size_t)(r0 + r) * D + c * 8),
                (las_t)(A + it * 2048 + wave * 512), 16, 0, 0);
    }

    // --- B fragments + bias while DMA is in flight ---
    bf16x8 B[4][2];
    float bias[2];
#pragma unroll
    for (int nt = 0; nt < 2; ++nt) {
        const int n = nh * 128 + wave * 32 + nt * 16 + l15;
        bias[nt] = half ? 0.f : b1[n];
#pragma unroll
        for (int kit = 0; kit < 4; ++kit)
            B[kit][nt] = *(const bf16x8*)(w1bf + (size_t)n * K2 + koff + kit * 32 + quad * 8);
    }

    __syncthreads();   // vmcnt(0): A landed

    f32x4 acc[4][2];
    const f32x4 zero = {0.f, 0.f, 0.f, 0.f};
#pragma unroll
    for (int ms = 0; ms < 4; ++ms)
#pragma unroll
        for (int nt = 0; nt < 2; ++nt)
            acc[ms][nt] = zero;

#pragma unroll
    for (int kit = 0; kit < 4; ++kit) {
        bf16x8 a[4];
#pragma unroll
        for (int ms = 0; ms < 4; ++ms) {
            const int row = ms * 16 + l15;
            const int p = (kit * 4 + quad) ^ l15;
            a[ms] = *(const bf16x8*)&A[row * 128 + p * 8];
        }
#pragma unroll
        for (int ms = 0; ms < 4; ++ms)
#pragma unroll
            for (int nt = 0; nt < 2; ++nt)
                acc[ms][nt] = __builtin_amdgcn_mfma_f32_16x16x32_bf16(
                    a[ms], B[kit][nt], acc[ms][nt], 0, 0, 0);
    }

    // --- direct permuted store: dword per (ms,r), 64B segment per quad ---
    const int coff = nh * 128 + wave * 32 + l15 * 2;   // short offset in U row
#pragma unroll
    for (int ms = 0; ms < 4; ++ms) {
#pragma unroll
        for (int r = 0; r < 4; ++r) {
            const int m = ms * 16 + quad * 4 + r;
            if (m < rows) {
                const unsigned lo = f2bf(acc[ms][0][r] + bias[0]);
                const unsigned hi = f2bf(acc[ms][1][r] + bias[1]);
                *(unsigned*)(U + (size_t)(r0 + m) * H + coff) = lo | (hi << 16);
            }
        }
    }
}

// ---------------- hist49: count + per-block range reservation --------------
// 256 blocks x 6250 edges. LDS count over 49 buckets; one atomicAdd per
// (block,bucket) reserves this block's slice within the bucket (12.5K total).
__global__ __launch_bounds__(256) void hist49(
    const int* __restrict__ srcE, int* __restrict__ gh, int* __restrict__ bOff)
{
    __shared__ int lh[NB2];
    const int tid = threadIdx.x;
    const int base = blockIdx.x * EPB;
    if (tid < NB2) lh[tid] = 0;
    __syncthreads();
    for (int i = tid; i < EPB; i += 256)
        atomicAdd(&lh[srcE[base + i] >> 11], 1);
    __syncthreads();
    if (tid < NB2)
        bOff[blockIdx.x * NB2 + tid] = atomicAdd(&gh[tid], lh[tid]);
}

// ---------------- scatter49: coalesced packed scatter + rank ---------------
// Each block recomputes the 49-prefix from gh (complete after hist49),
// scatters edges as uint64 (src:17 | dst:17) into sorted position p, and
// writes rank[e] = p (address coalesced, value random) for the unscatter.
__global__ __launch_bounds__(256) void scatter49(
    const int* __restrict__ srcE, const int* __restrict__ dstE,
    const int* __restrict__ gh, const int* __restrict__ bOff,
    unsigned long long* __restrict__ pk, int* __restrict__ rank)
{
    __shared__ int pref[NB2];
    __shared__ int lcur[NB2];
    const int tid = threadIdx.x;
    const int base = blockIdx.x * EPB;
    if (tid == 0) {
        int s = 0;
        for (int b = 0; b < NB2; ++b) { pref[b] = s; s += gh[b]; }
    }
    if (tid < NB2) lcur[tid] = bOff[blockIdx.x * NB2 + tid];
    __syncthreads();
    for (int i = tid; i < EPB; i += 256) {
        const int e = base + i;
        const int s = srcE[e];
        const int d = dstE[e];
        const int b = s >> 11;
        const int r = atomicAdd(&lcur[b], 1);
        const int p = pref[b] + r;
        pk[(size_t)p] = (unsigned long long)s | ((unsigned long long)d << 17);
        rank[e] = p;
    }
}

// ---------------- edge pass (sorted packed, coalesced writes) --------------
// U' layout: within each 32-col block, c'' = l15*2+nt holds n'' = nt*16+l15.
// 16-lane group handles 8 consecutive 4-edge chunks (32 sorted edges).
// Blocks xcd_chunk-swizzled: contiguous sorted ranges stay on one XCD ->
// each 1 MB src-bucket Us window is fetched ~once into that XCD's L2.
// Scores written COALESCED at the sorted position (no RFO); unscatter
// permutes them back with random READS instead.
__global__ __launch_bounds__(256) void edge_score_pk(
    const unsigned short* __restrict__ Us,
    const unsigned short* __restrict__ Ud,
    const unsigned long long* __restrict__ pk,
    const float* __restrict__ w2,
    const float* __restrict__ b2p,
    float* __restrict__ ssort)
{
    const int b = xcd_chunk(blockIdx.x, gridDim.x);
    const int tid = threadIdx.x;
    const int l = tid & 15;
    const int grp = b * 16 + (tid >> 4);   // 0..49999

    float w2v[16];
#pragma unroll
    for (int j = 0; j < 16; ++j) {
        const int cp = l * 16 + j;
        const int n = (cp & ~31) + ((cp & 1) << 4) + ((cp & 31) >> 1);
        w2v[j] = w2[n];
    }
    const float b2 = *b2p;

    const int g0 = grp * 8;
    for (int g = g0; g < g0 + 8; ++g) {
        const int e0 = g * 4;
        const uint4 pa = *(const uint4*)(pk + e0);       // edges 0,1
        const uint4 pb = *(const uint4*)(pk + e0 + 2);   // edges 2,3
        const unsigned lo[4] = {pa.x, pa.z, pb.x, pb.z};
        const unsigned hi[4] = {pa.y, pa.w, pb.y, pb.w};
        int sv[4], dv[4];
#pragma unroll
        for (int k = 0; k < 4; ++k) {
            sv[k] = lo[k] & 0x1FFFF;
            dv[k] = ((lo[k] >> 17) | (hi[k] << 15)) & 0x1FFFF;
        }

        bf16x8 u[4][2], v[4][2];
#pragma unroll
        for (int k = 0; k < 4; ++k) {
            const bf16x8* us = (const bf16x8*)(Us + (size_t)sv[k] * H + l * 16);
            const bf16x8* ud = (const bf16x8*)(Ud + (size_t)dv[k] * H + l * 16);
            u[k][0] = us[0]; u[k][1] = us[1];
            v[k][0] = ud[0]; v[k][1] = ud[1];
        }

        float4 res;
        float* resp = (float*)&res;
#pragma unroll
        for (int k = 0; k < 4; ++k) {
            float acc = 0.f;
#pragma unroll
            for (int j = 0; j < 8; ++j) {
                float hv = bf2f((unsigned short)u[k][0][j]) + bf2f((unsigned short)v[k][0][j]);
                acc = fmaf(fmaxf(hv, 0.f), w2v[j], acc);
            }
#pragma unroll
            for (int j = 0; j < 8; ++j) {
                float hv = bf2f((unsigned short)u[k][1][j]) + bf2f((unsigned short)v[k][1][j]);
                acc = fmaf(fmaxf(hv, 0.f), w2v[j + 8], acc);
            }
            acc += __shfl_xor(acc, 1, 16);
            acc += __shfl_xor(acc, 2, 16);
            acc += __shfl_xor(acc, 4, 16);
            acc += __shfl_xor(acc, 8, 16);
            resp[k] = acc + b2;
        }
        if (l == 0) *(float4*)(ssort + e0) = res;   // coalesced
    }
}

// ---------------- unscatter: out[e] = ssort[rank[e]] -----------------------
// Coalesced rank read, random dword READ over 6.4 MB (line-shared, no RFO),
// coalesced float4 out write.
__global__ __launch_bounds__(256) void unscatter(
    const float* __restrict__ ssort, const int* __restrict__ rank,
    float* __restrict__ out)
{
    const int g = blockIdx.x * 256 + threadIdx.x;   // 4-edge group
    if (g >= E_TOTAL / 4) return;
    const int e0 = g * 4;
    const int4 r4 = *(const int4*)(rank + e0);
    float4 o;
    o.x = ssort[r4.x];
    o.y = ssort[r4.y];
    o.z = ssort[r4.z];
    o.w = ssort[r4.w];
    *(float4*)(out + e0) = o;
}

// ---------------- edge pass (R12 unsorted, mid-ws fallback) ----------------
__global__ __launch_bounds__(256) void edge_score(
    const unsigned short* __restrict__ Us,
    const unsigned short* __restrict__ Ud,
    const int* __restrict__ srcE,
    const int* __restrict__ dstE,
    const float* __restrict__ w2,
    const float* __restrict__ b2p,
    float* __restrict__ out)
{
    const int gt = blockIdx.x * 256 + threadIdx.x;
    const int l = gt & 15;
    const int q = gt >> 4;
    const int Q = (gridDim.x * 256) >> 4;
    const int NGRP = E_TOTAL / 4;   // 400000

    float w2v[16];
#pragma unroll
    for (int j = 0; j < 16; ++j) {
        const int cp = l * 16 + j;
        const int n = (cp & ~31) + ((cp & 1) << 4) + ((cp & 31) >> 1);
        w2v[j] = w2[n];
    }
    const float b2 = *b2p;

    for (int g = q; g < NGRP; g += Q) {
        const int e0 = g * 4;
        const int4 s4 = *(const int4*)(srcE + e0);
        const int4 d4 = *(const int4*)(dstE + e0);
        const int sv[4] = {s4.x, s4.y, s4.z, s4.w};
        const int dv[4] = {d4.x, d4.y, d4.z, d4.w};

        bf16x8 u[4][2], v[4][2];
#pragma unroll
        for (int k = 0; k < 4; ++k) {
            const bf16x8* us = (const bf16x8*)(Us + (size_t)sv[k] * H + l * 16);
            const bf16x8* ud = (const bf16x8*)(Ud + (size_t)dv[k] * H + l * 16);
            u[k][0] = us[0]; u[k][1] = us[1];
            v[k][0] = ud[0]; v[k][1] = ud[1];
        }

        float4 res;
        float* resp = (float*)&res;
#pragma unroll
        for (int k = 0; k < 4; ++k) {
            float acc = 0.f;
#pragma unroll
            for (int j = 0; j < 8; ++j) {
                float hv = bf2f((unsigned short)u[k][0][j]) + bf2f((unsigned short)v[k][0][j]);
                acc = fmaf(fmaxf(hv, 0.f), w2v[j], acc);
            }
#pragma unroll
            for (int j = 0; j < 8; ++j) {
                float hv = bf2f((unsigned short)u[k][1][j]) + bf2f((unsigned short)v[k][1][j]);
                acc = fmaf(fmaxf(hv, 0.f), w2v[j + 8], acc);
            }
            acc += __shfl_xor(acc, 1, 16);
            acc += __shfl_xor(acc, 2, 16);
            acc += __shfl_xor(acc, 4, 16);
            acc += __shfl_xor(acc, 8, 16);
            resp[k] = acc + b2;
        }
        if (l == 0) *(float4*)(out + e0) = res;
    }
}

// ======================= R4 fallback (ws too small) ======================

#define TILE_M 32
#define NTILES (E_TOTAL / TILE_M)
#define GRID 2500

#if defined(__has_attribute)
#if __has_attribute(amdgpu_waves_per_eu)
#define LB __launch_bounds__(256) __attribute__((amdgpu_waves_per_eu(2, 2)))
#else
#define LB __launch_bounds__(256, 2)
#endif
#else
#define LB __launch_bounds__(256, 2)
#endif

__global__ LB void edge_mlp(
    const unsigned short* __restrict__ hbf,
    const int* __restrict__ srcE,
    const int* __restrict__ dstE,
    const unsigned short* __restrict__ w1bf,
    const float* __restrict__ b1,
    const float* __restrict__ w2,
    const float* __restrict__ b2p,
    float* __restrict__ out)
{
    __shared__ __align__(16) unsigned short X[2][TILE_M * K2];
    __shared__ float red[2][TILE_M][5];

    const int tid = threadIdx.x;
    const int wave = tid >> 6;
    const int lane = tid & 63;
    const int lane15 = lane & 15;
    const int quad = lane >> 4;

    bf16x8 B[8][4];
#pragma unroll
    for (int kit = 0; kit < 8; ++kit)
#pragma unroll
        for (int nt = 0; nt < 4; ++nt) {
            int n = wave * 64 + nt * 16 + lane15;
            int k = kit * 32 + quad * 8;
            B[kit][nt] = *(const bf16x8*)(w1bf + n * K2 + k);
        }

    float b1v[4], w2v[4];
#pragma unroll
    for (int nt = 0; nt < 4; ++nt) {
        int n = wave * 64 + nt * 16 + lane15;
        b1v[nt] = b1[n];
        w2v[nt] = w2[n];
    }
    const float b2 = *b2p;

    const int r_off = tid >> 5;
    const int c = (tid & 31) ^ (r_off & 7);
    const int half = c >> 4;
    const int fc = c & 15;
    const int* idx_base = half ? dstE : srcE;
    const int gshort = fc * 8;

    const int t0 = blockIdx.x;
    int inode[4];

#pragma unroll
    for (int it = 0; it < 4; ++it)
        inode[it] = idx_base[t0 * TILE_M + it * 8 + r_off];
#pragma unroll
    for (int it = 0; it < 4; ++it)
        __builtin_amdgcn_global_load_lds(
            (gas_t)(hbf + inode[it] * D + gshort),
            (las_t)(&X[0][0] + it * 2048 + wave * 512), 16, 0, 0);
    {
        const int t1 = t0 + GRID;
#pragma unroll
        for (int it = 0; it < 4; ++it)
            inode[it] = idx_base[t1 * TILE_M + it * 8 + r_off];
    }

    int buf = 0;
    int prev_eb = -1;

    for (int tile = t0; tile < NTILES; tile += GRID) {
        __syncthreads();

        const int nt1 = tile + GRID;
        if (nt1 < NTILES) {
            unsigned short* Xn = &X[buf ^ 1][0];
#pragma unroll
            for (int it = 0; it < 4; ++it)
                __builtin_amdgcn_global_load_lds(
                    (gas_t)(hbf + inode[it] * D + gshort),
                    (las_t)(Xn + it * 2048 + wave * 512), 16, 0, 0);
        }
        const int nt2 = tile + 2 * GRID;
        if (nt2 < NTILES) {
            const int eb2 = nt2 * TILE_M;
#pragma unroll
            for (int it = 0; it < 4; ++it)
                inode[it] = idx_base[eb2 + it * 8 + r_off];
        }
        if (prev_eb >= 0 && tid < TILE_M) {
            float s = b2;
#pragma unroll
            for (int w = 0; w < 4; ++w) s += red[buf ^ 1][tid][w];
            out[prev_eb + tid] = s;
        }

        const unsigned short* Xc = &X[buf][0];
        f32x4 acc[2][4];
        const f32x4 zero = {0.f, 0.f, 0.f, 0.f};
#pragma unroll
        for (int ms = 0; ms < 2; ++ms)
#pragma unroll
            for (int nt = 0; nt < 4; ++nt)
                acc[ms][nt] = zero;

#pragma unroll
        for (int kit = 0; kit < 8; ++kit) {
            const int p8 = (((kit * 4 + quad) ^ (lane15 & 7))) * 8;
            bf16x8 a[2];
#pragma unroll
            for (int ms = 0; ms < 2; ++ms)
                a[ms] = *(const bf16x8*)&Xc[(ms * 16 + lane15) * K2 + p8];
#pragma unroll
            for (int ms = 0; ms < 2; ++ms)
#pragma unroll
                for (int nt = 0; nt < 4; ++nt)
                    acc[ms][nt] = __builtin_amdgcn_mfma_f32_16x16x32_bf16(
                        a[ms], B[kit][nt], acc[ms][nt], 0, 0, 0);
        }

#pragma unroll
        for (int ms = 0; ms < 2; ++ms)
#pragma unroll
            for (int r = 0; r < 4; ++r) {
                float p = 0.f;
#pragma unroll
                for (int nt = 0; nt < 4; ++nt) {
                    float hv = acc[ms][nt][r] + b1v[nt];
                    p = fmaf(fmaxf(hv, 0.f), w2v[nt], p);
                }
                p += __shfl_xor(p, 1, 16);
                p += __shfl_xor(p, 2, 16);
                p += __shfl_xor(p, 4, 16);
                p += __shfl_xor(p, 8, 16);
                if (lane15 == 0) red[buf][ms * 16 + quad * 4 + r][wave] = p;
            }
        prev_eb = tile * TILE_M;
        buf ^= 1;
    }

    __syncthreads();
    if (prev_eb >= 0 && tid < TILE_M) {
        float s = b2;
#pragma unroll
        for (int w = 0; w < 4; ++w) s += red[buf ^ 1][tid][w];
        out[prev_eb + tid] = s;
    }
}

// ================================ launch ================================

extern "C" void kernel_launch(void* const* d_in, const int* in_sizes, int n_in,
                              void* d_out, int out_size, void* d_ws, size_t ws_size,
                              hipStream_t stream) {
    const float* h    = (const float*)d_in[0];
    const int*   srcE = (const int*)d_in[1];
    const int*   dstE = (const int*)d_in[2];
    const float* W1   = (const float*)d_in[3];
    const float* b1   = (const float*)d_in[4];
    const float* w2   = (const float*)d_in[5];
    const float* b2   = (const float*)d_in[6];
    float* out = (float*)d_out;

    char* ws = (char*)d_ws;
    const size_t offUs   = 0;                        // 51,200,000 B
    const size_t offUd   = 51200000;                 // 51,200,000 B
    const size_t offHbf  = 102400000;                // 25,600,000 B
    const size_t offW1bf = 128000000;                // 131,072 B
    const size_t need    = offW1bf + 131072;         // 128,131,072 B
    // R18 sort extras (rank/ssort alias the dead hbf region after u_gemm3)
    const size_t offGh   = need;                     // 49 ints (pad 4096)
    const size_t offBO   = offGh + 4096;             // 256*49 ints (pad 65536)
    const size_t offPK   = offBO + 65536;            // 12,800,000 B (uint64/edge)
    const size_t need2   = offPK + 12800000;         // 141,000,704 B

    if (ws_size >= need) {
        unsigned short* Us   = (unsigned short*)(ws + offUs);
        unsigned short* Ud   = (unsigned short*)(ws + offUd);
        unsigned short* hbf  = (unsigned short*)(ws + offHbf);
        unsigned short* w1bf = (unsigned short*)(ws + offW1bf);
        const bool sorted = (ws_size >= need2);
        int* gh  = (int*)(ws + offGh);
        int* bO  = (int*)(ws + offBO);
        unsigned long long* pk = (unsigned long long*)(ws + offPK);
        // reuse dead hbf region: rank (6.4 MB) + score_sorted (6.4 MB) <= 25.6 MB
        int*   rank  = (int*)(ws + offHbf);
        float* ssort = (float*)(ws + offHbf + 6400000);

        int n4h = NNODES * D / 4, n4w = H * K2 / 4;
        const int nz = sorted ? NB2 : 0;
        cvt_kernel<<<(n4h + n4w + nz + 255) / 256, 256, 0, stream>>>(
            h, W1, hbf, w1bf, n4h, n4w, gh, nz);
        u_gemm3<<<4 * ((NNODES + 63) / 64), 256, 0, stream>>>(hbf, w1bf, b1, Us, Ud);
        if (sorted) {
            hist49<<<SORT_GRID, 256, 0, stream>>>(srcE, gh, bO);
            scatter49<<<SORT_GRID, 256, 0, stream>>>(srcE, dstE, gh, bO, pk, rank);
            edge_score_pk<<<EDGE_GRID, 256, 0, stream>>>(Us, Ud, pk, w2, b2, ssort);
            unscatter<<<(E_TOTAL / 4 + 255) / 256, 256, 0, stream>>>(ssort, rank, out);
        } else {
            edge_score<<<4096, 256, 0, stream>>>(Us, Ud, srcE, dstE, w2, b2, out);
        }
    } else {
        unsigned short* hbf  = (unsigned short*)d_ws;
        unsigned short* w1bf = hbf + (size_t)NNODES * D;
        int n4h = NNODES * D / 4, n4w = H * K2 / 4;
        cvt_kernel<<<(n4h + n4w + 255) / 256, 256, 0, stream>>>(
            h, W1, hbf, w1bf, n4h, n4w, nullptr, 0);
        edge_mlp<<<GRID, 256, 0, stream>>>(hbf, srcE, dstE, w1bf, b1, w2, b2, out);
    }
}